// Round 6
// baseline (525.966 us; speedup 1.0000x reference)
//
#include <hip/hip_runtime.h>
#include <hip/hip_bf16.h>

// Problem constants
#define BB 2
#define LL 1024
#define DD 1024
#define DI 2048
#define SS 16
#define KK 4
#define RR 64
#define MROWS (BB*LL)   // 2048
#define NCH 8           // scan chunks
#define CLEN 128        // chunk length
#define NSCAN (BB*DI*SS*NCH)   // 524288 scan lanes

typedef __attribute__((ext_vector_type(8))) short short8;     // 8 bf16 = 4 VGPR
typedef __attribute__((ext_vector_type(4))) float floatx4;    // MFMA C/D

// RNE fp32 -> bf16 bits
__device__ __forceinline__ unsigned short f2bf(float v) {
    unsigned int u = __float_as_uint(v);
    return (unsigned short)((u + 0x7FFFu + ((u >> 16) & 1u)) >> 16);
}
__device__ __forceinline__ float bf2f(unsigned short h) {
    return __uint_as_float(((unsigned int)h) << 16);
}
__device__ __forceinline__ void split1(float v, unsigned short& a,
                                       unsigned short& b, unsigned short& c) {
    a = f2bf(v);
    float r = v - bf2f(a);
    b = f2bf(r);
    float r2 = r - bf2f(b);
    c = f2bf(r2);
}

// ---------------------------------------------------------------------------
// split3: fp32[n] -> three bf16[n] (hi, mid, lo), elementwise
// ---------------------------------------------------------------------------
__global__ __launch_bounds__(256) void split3(const float4* __restrict__ src,
                                              ushort4* __restrict__ d1,
                                              ushort4* __restrict__ d2,
                                              ushort4* __restrict__ d3, int n4) {
    for (int i = blockIdx.x * 256 + threadIdx.x; i < n4; i += gridDim.x * 256) {
        const float4 v = src[i];
        ushort4 o1, o2, o3;
        split1(v.x, o1.x, o2.x, o3.x);
        split1(v.y, o1.y, o2.y, o3.y);
        split1(v.z, o1.z, o2.z, o3.z);
        split1(v.w, o1.w, o2.w, o3.w);
        d1[i] = o1; d2[i] = o2; d3[i] = o3;
    }
}

// ---------------------------------------------------------------------------
// split3_t: src [2048][2048] (k-major) -> three bf16 [M][K] (transposed)
// ---------------------------------------------------------------------------
__global__ __launch_bounds__(256) void split3_t(const float* __restrict__ src,
                                                unsigned short* __restrict__ d1,
                                                unsigned short* __restrict__ d2,
                                                unsigned short* __restrict__ d3) {
    __shared__ float xs[64][68];
    const int m0 = blockIdx.x * 64;
    const int k0 = blockIdx.y * 64;
    const int tid = threadIdx.x;
    {
        const int r = tid >> 2;
        const int cb = (tid & 3) * 16;
#pragma unroll
        for (int i = 0; i < 4; ++i) {
            float4 v = *(const float4*)&src[(size_t)(k0 + r) * 2048 + m0 + cb + i * 4];
            *(float4*)&xs[r][cb + i * 4] = v;
        }
    }
    __syncthreads();
    const int mm = tid >> 2;
    const int kb = (tid & 3) * 16;
    const size_t obase = (size_t)(m0 + mm) * 2048 + k0 + kb;
#pragma unroll
    for (int g = 0; g < 4; ++g) {
        ushort4 o1, o2, o3;
        split1(xs[kb + g * 4 + 0][mm], o1.x, o2.x, o3.x);
        split1(xs[kb + g * 4 + 1][mm], o1.y, o2.y, o3.y);
        split1(xs[kb + g * 4 + 2][mm], o1.z, o2.z, o3.z);
        split1(xs[kb + g * 4 + 3][mm], o1.w, o2.w, o3.w);
        *(ushort4*)&d1[obase + g * 4] = o1;
        *(ushort4*)&d2[obase + g * 4] = o2;
        *(ushort4*)&d3[obase + g * 4] = o3;
    }
}

// ---------------------------------------------------------------------------
// Split-bf16 MFMA GEMM (unchanged)
// ---------------------------------------------------------------------------
__global__ __launch_bounds__(256, 2) void gemm_mfma_split(
    const unsigned short* __restrict__ A1, const unsigned short* __restrict__ A2,
    const unsigned short* __restrict__ A3,
    const unsigned short* __restrict__ B1, const unsigned short* __restrict__ B2,
    const unsigned short* __restrict__ B3,
    float* __restrict__ C0, float* __restrict__ C1,
    int M, int N, int Kstride, int Klen) {
    __shared__ unsigned short As[3][128][40];
    __shared__ unsigned short Bs[3][128][40];
    const int tid = threadIdx.x;
    const int bm = blockIdx.y * 128;
    const int bn = blockIdx.x * 128;
    const int Koff = blockIdx.z * Klen;
    float* __restrict__ C = blockIdx.z ? C1 : C0;

    const int lane = tid & 63;
    const int wv = tid >> 6;
    const int lm = lane & 15;
    const int kq = lane >> 4;
    const int wm = (wv >> 1) * 64;
    const int wn = (wv & 1) * 64;

    floatx4 acc[4][4];
    const floatx4 zf = {0.f, 0.f, 0.f, 0.f};
#pragma unroll
    for (int i = 0; i < 4; ++i)
#pragma unroll
        for (int j = 0; j < 4; ++j) acc[i][j] = zf;

    const int ch0 = tid * 2;

    for (int kt = Koff; kt < Koff + Klen; kt += 32) {
#define STAGE(p, SRC_A, SRC_B)                                                          \
        {                                                                               \
            const int r0 = (ch0) >> 2, c0 = ((ch0) & 3) * 8;                            \
            const int r1 = (ch0 + 1) >> 2, c1 = ((ch0 + 1) & 3) * 8;                    \
            *(short8*)&As[p][r0][c0] = *(const short8*)&SRC_A[(size_t)(bm + r0) * Kstride + kt + c0]; \
            *(short8*)&As[p][r1][c1] = *(const short8*)&SRC_A[(size_t)(bm + r1) * Kstride + kt + c1]; \
            *(short8*)&Bs[p][r0][c0] = *(const short8*)&SRC_B[(size_t)(bn + r0) * Kstride + kt + c0]; \
            *(short8*)&Bs[p][r1][c1] = *(const short8*)&SRC_B[(size_t)(bn + r1) * Kstride + kt + c1]; \
        }
        STAGE(0, A1, B1)
        STAGE(1, A2, B2)
        STAGE(2, A3, B3)
#undef STAGE
        __syncthreads();

        short8 af[3][4];
#pragma unroll
        for (int p = 0; p < 3; ++p)
#pragma unroll
            for (int i = 0; i < 4; ++i)
                af[p][i] = *(const short8*)&As[p][wm + i * 16 + lm][kq * 8];

#define PROD(p, bfq)                                                                     \
        _Pragma("unroll")                                                                \
        for (int i = 0; i < 4; ++i)                                                      \
            _Pragma("unroll")                                                            \
            for (int j = 0; j < 4; ++j)                                                  \
                acc[i][j] = __builtin_amdgcn_mfma_f32_16x16x32_bf16(af[p][i], bfq[j],    \
                                                                    acc[i][j], 0, 0, 0);
        {
            short8 bfq[4];
#pragma unroll
            for (int j = 0; j < 4; ++j) bfq[j] = *(const short8*)&Bs[0][wn + j * 16 + lm][kq * 8];
            PROD(0, bfq)
            PROD(1, bfq)
            PROD(2, bfq)
        }
        {
            short8 bfq[4];
#pragma unroll
            for (int j = 0; j < 4; ++j) bfq[j] = *(const short8*)&Bs[1][wn + j * 16 + lm][kq * 8];
            PROD(0, bfq)
            PROD(1, bfq)
        }
        {
            short8 bfq[4];
#pragma unroll
            for (int j = 0; j < 4; ++j) bfq[j] = *(const short8*)&Bs[2][wn + j * 16 + lm][kq * 8];
            PROD(0, bfq)
        }
#undef PROD
        __syncthreads();
    }

#pragma unroll
    for (int i = 0; i < 4; ++i) {
        const int mrow = bm + wm + i * 16 + kq * 4;
#pragma unroll
        for (int j = 0; j < 4; ++j) {
            const int col = bn + wn + j * 16 + lm;
#pragma unroll
            for (int r = 0; r < 4; ++r)
                C[(size_t)(mrow + r) * N + col] = acc[i][j][r];
        }
    }
}

// ---------------------------------------------------------------------------
__global__ __launch_bounds__(256) void reduce_add_inplace(float4* __restrict__ dst,
                                                          const float4* __restrict__ src,
                                                          int n4) {
    for (int i = blockIdx.x * 256 + threadIdx.x; i < n4; i += gridDim.x * 256) {
        float4 a = dst[i];
        const float4 b = src[i];
        a.x += b.x; a.y += b.y; a.z += b.z; a.w += b.w;
        dst[i] = a;
    }
}

// ---------------------------------------------------------------------------
// Depthwise causal conv (K=4) + bias + silu, transposed outputs (unchanged)
// ---------------------------------------------------------------------------
#define CTT 64
#define CCC 32
__global__ __launch_bounds__(256) void conv_silu_t(const float* __restrict__ xz,
                                                   const float* __restrict__ Wc,
                                                   const float* __restrict__ bc,
                                                   float* __restrict__ u_t,
                                                   float* __restrict__ zs_t) {
    __shared__ float xs[CTT + 3][CCC];
    __shared__ float zsh[CTT][CCC];
    const int c0 = blockIdx.x * CCC;
    const int t0 = blockIdx.y * CTT;
    const int b = blockIdx.z;
    const int tid = threadIdx.x;
    const int lc = tid & 31;
    const int lt = tid >> 5;
    const float* xb = xz + (size_t)b * LL * (2 * DI);

#pragma unroll
    for (int i = 0; i < 9; ++i) {
        const int r = lt + i * 8;
        if (r < CTT + 3) {
            const int t = t0 - 3 + r;
            xs[r][lc] = (t >= 0) ? xb[(size_t)t * (2 * DI) + c0 + lc] : 0.f;
        }
    }
#pragma unroll
    for (int i = 0; i < 8; ++i) {
        const int r = lt + i * 8;
        zsh[r][lc] = xb[(size_t)(t0 + r) * (2 * DI) + DI + c0 + lc];
    }
    __syncthreads();

    const int c = c0 + lc;
    const float w0 = Wc[c * 4 + 0], w1 = Wc[c * 4 + 1];
    const float w2 = Wc[c * 4 + 2], w3 = Wc[c * 4 + 3];
    const float bcv = bc[c];
    const int tb = lt * 8;
    float uo[8], zo[8];
#pragma unroll
    for (int j = 0; j < 8; ++j) {
        const int r = tb + j;
        float acc = bcv + xs[r][lc] * w0 + xs[r + 1][lc] * w1
                        + xs[r + 2][lc] * w2 + xs[r + 3][lc] * w3;
        uo[j] = acc / (1.f + __expf(-acc));
        const float zv = zsh[r][lc];
        zo[j] = zv / (1.f + __expf(-zv));
    }
    const size_t m0 = (size_t)b * LL + t0 + tb;
    float* utp = u_t + (size_t)c * MROWS + m0;
    *(float4*)&utp[0] = make_float4(uo[0], uo[1], uo[2], uo[3]);
    *(float4*)&utp[4] = make_float4(uo[4], uo[5], uo[6], uo[7]);
    float* ztp = zs_t + (size_t)c * MROWS + m0;
    *(float4*)&ztp[0] = make_float4(zo[0], zo[1], zo[2], zo[3]);
    *(float4*)&ztp[4] = make_float4(zo[4], zo[5], zo[6], zo[7]);
}

// ---------------------------------------------------------------------------
// proj: Pt[n][m] (unchanged)
// ---------------------------------------------------------------------------
__global__ __launch_bounds__(256) void proj_gemm_t(const float* __restrict__ u_t,
                                                   const float* __restrict__ Wx,
                                                   float* __restrict__ Pt) {
    const int BKp = 64;
    __shared__ float Us[16][BKp + 1];
    __shared__ float Ws[96][BKp + 1];
    const int tid = threadIdx.x;
    const int m0 = blockIdx.x * 16;
    const int tx = tid & 31;
    const int ty = tid >> 5;
    float acc[2][3] = {{0.f, 0.f, 0.f}, {0.f, 0.f, 0.f}};

    for (int kt = 0; kt < DI; kt += BKp) {
#pragma unroll
        for (int i = 0; i < 4; ++i) {
            const int idx = tid + i * 256;
            const int mm = idx & 15;
            const int cc = idx >> 4;
            Us[mm][cc] = u_t[(size_t)(kt + cc) * MROWS + m0 + mm];
        }
#pragma unroll
        for (int i = 0; i < 6; ++i) {
            const int idx = tid + i * 256;
            const int r = idx >> 4;
            const int c4 = (idx & 15) << 2;
            float4 v = *(const float4*)&Wx[(size_t)r * DI + kt + c4];
            Ws[r][c4] = v.x; Ws[r][c4 + 1] = v.y; Ws[r][c4 + 2] = v.z; Ws[r][c4 + 3] = v.w;
        }
        __syncthreads();
#pragma unroll 8
        for (int k = 0; k < BKp; ++k) {
            const float um0 = Us[ty * 2][k];
            const float um1 = Us[ty * 2 + 1][k];
#pragma unroll
            for (int j = 0; j < 3; ++j) {
                const float w = Ws[tx + 32 * j][k];
                acc[0][j] += um0 * w;
                acc[1][j] += um1 * w;
            }
        }
        __syncthreads();
    }
#pragma unroll
    for (int i = 0; i < 2; ++i)
#pragma unroll
        for (int j = 0; j < 3; ++j)
            Pt[(size_t)(tx + 32 * j) * MROWS + m0 + ty * 2 + i] = acc[i][j];
}

// ---------------------------------------------------------------------------
// dt_t[c][m] (unchanged)
// ---------------------------------------------------------------------------
__global__ __launch_bounds__(256) void dt_gemm_t(const float* __restrict__ Pt,
                                                 const float* __restrict__ Wdt,
                                                 const float* __restrict__ bdt,
                                                 float* __restrict__ dtb_t) {
    __shared__ float ps[64][16];
    const int tid = threadIdx.x;
    const int c = blockIdx.x * 256 + tid;
    const int m0 = blockIdx.y * 16;
#pragma unroll
    for (int i = 0; i < 4; ++i) {
        const int idx = tid + 256 * i;
        const int r = idx >> 4;
        const int mm = idx & 15;
        ps[r][mm] = Pt[(size_t)r * MROWS + m0 + mm];
    }
    float w[64];
#pragma unroll
    for (int r4 = 0; r4 < 64; r4 += 4) {
        float4 v = *(const float4*)&Wdt[(size_t)c * 64 + r4];
        w[r4] = v.x; w[r4 + 1] = v.y; w[r4 + 2] = v.z; w[r4 + 3] = v.w;
    }
    const float bd = bdt[c];
    __syncthreads();
    float acc[16];
#pragma unroll
    for (int m = 0; m < 16; ++m) acc[m] = bd;
    for (int r = 0; r < 64; ++r) {
        const float wr = w[r];
        const float4 p0 = *(const float4*)&ps[r][0];
        const float4 p1 = *(const float4*)&ps[r][4];
        const float4 p2 = *(const float4*)&ps[r][8];
        const float4 p3 = *(const float4*)&ps[r][12];
        acc[0] += p0.x * wr;  acc[1] += p0.y * wr;  acc[2] += p0.z * wr;  acc[3] += p0.w * wr;
        acc[4] += p1.x * wr;  acc[5] += p1.y * wr;  acc[6] += p1.z * wr;  acc[7] += p1.w * wr;
        acc[8] += p2.x * wr;  acc[9] += p2.y * wr;  acc[10] += p2.z * wr; acc[11] += p2.w * wr;
        acc[12] += p3.x * wr; acc[13] += p3.y * wr; acc[14] += p3.z * wr; acc[15] += p3.w * wr;
    }
    float o[16];
#pragma unroll
    for (int m = 0; m < 16; ++m) {
        const float a = acc[m];
        o[m] = (a > 20.f) ? a : __logf(1.f + __expf(a));
    }
    float* dp = dtb_t + (size_t)c * MROWS + m0;
    *(float4*)&dp[0]  = make_float4(o[0], o[1], o[2], o[3]);
    *(float4*)&dp[4]  = make_float4(o[4], o[5], o[6], o[7]);
    *(float4*)&dp[8]  = make_float4(o[8], o[9], o[10], o[11]);
    *(float4*)&dp[12] = make_float4(o[12], o[13], o[14], o[15]);
}

// ---------------------------------------------------------------------------
// Chunked scan pass 1: local scan per (b,c,s,chunk) from h=0.
// prodA accumulated in double to keep the combine near-exact.
// ---------------------------------------------------------------------------
__global__ __launch_bounds__(256) void scan_part1(const float* __restrict__ dtb_t,
                                                  const float* __restrict__ u_t,
                                                  const float* __restrict__ Pt,
                                                  const float* __restrict__ A_log,
                                                  float* __restrict__ hend,
                                                  float* __restrict__ prodA) {
    const int g = blockIdx.x * 256 + threadIdx.x;
    const int s = g & 15;
    const int ch = (g >> 4) & (NCH - 1);
    const int cg = g >> 7;              // b*DI + c
    const int c = cg & (DI - 1);
    const int b = cg >> 11;
    const float Aval = -expf(A_log[c * 16 + s]);

    const size_t base = (size_t)c * MROWS + (size_t)b * LL + ch * CLEN;
    const float* dtp = dtb_t + base;
    const float* up  = u_t   + base;
    const float* Bp  = Pt + (size_t)(64 + s) * MROWS + (size_t)b * LL + ch * CLEN;

    float h = 0.f;
    double pr = 1.0;
#pragma unroll 1
    for (int tg = 0; tg < CLEN; tg += 8) {
        float4 d0 = *(const float4*)(dtp + tg);  float4 d1 = *(const float4*)(dtp + tg + 4);
        float4 u0 = *(const float4*)(up + tg);   float4 u1 = *(const float4*)(up + tg + 4);
        float4 B0 = *(const float4*)(Bp + tg);   float4 B1 = *(const float4*)(Bp + tg + 4);
#define S1(dtv, uv, Bv) {                          \
        const float ab = __expf((dtv) * Aval);     \
        h = ab * h + ((dtv) * (Bv)) * (uv);        \
        pr *= (double)ab; }
        S1(d0.x, u0.x, B0.x) S1(d0.y, u0.y, B0.y) S1(d0.z, u0.z, B0.z) S1(d0.w, u0.w, B0.w)
        S1(d1.x, u1.x, B1.x) S1(d1.y, u1.y, B1.y) S1(d1.z, u1.z, B1.z) S1(d1.w, u1.w, B1.w)
#undef S1
    }
    hend[g] = h;
    prodA[g] = (float)pr;
}

// ---------------------------------------------------------------------------
// Pass 2: sequential combine over chunks per (b,c,s) -> hstart per chunk.
// ---------------------------------------------------------------------------
__global__ __launch_bounds__(256) void scan_part2(const float* __restrict__ hend,
                                                  const float* __restrict__ prodA,
                                                  float* __restrict__ hstart) {
    const int id = blockIdx.x * 256 + threadIdx.x;   // (b*DI+c)*16 + s
    const int s = id & 15;
    const int cg = id >> 4;
    float hs = 0.f;
#pragma unroll
    for (int ch = 0; ch < NCH; ++ch) {
        const int ix = s + (ch << 4) + (cg << 7);
        hstart[ix] = hs;
        hs = prodA[ix] * hs + hend[ix];
    }
}

// ---------------------------------------------------------------------------
// Pass 3: re-run scan per chunk from hstart, with y-reduction + gating.
// ---------------------------------------------------------------------------
__global__ __launch_bounds__(256) void scan_part3(const float* __restrict__ dtb_t,
                                                  const float* __restrict__ u_t,
                                                  const float* __restrict__ Pt,
                                                  const float* __restrict__ zs_t,
                                                  const float* __restrict__ A_log,
                                                  const float* __restrict__ hstart,
                                                  float* __restrict__ gated_t) {
    const int g = blockIdx.x * 256 + threadIdx.x;
    const int s = g & 15;
    const int ch = (g >> 4) & (NCH - 1);
    const int cg = g >> 7;
    const int c = cg & (DI - 1);
    const int b = cg >> 11;
    const float Aval = -expf(A_log[c * 16 + s]);

    const size_t base = (size_t)c * MROWS + (size_t)b * LL + ch * CLEN;
    const float* dtp = dtb_t + base;
    const float* up  = u_t   + base;
    const float* zp  = zs_t  + base;
    const float* Bp  = Pt + (size_t)(64 + s) * MROWS + (size_t)b * LL + ch * CLEN;
    const float* Cp  = Pt + (size_t)(80 + s) * MROWS + (size_t)b * LL + ch * CLEN;
    float* gp = gated_t + base;

    float h = hstart[g];

#define S3(dtv, uv, Bv, Cv, yy) {                  \
        const float ab = __expf((dtv) * Aval);     \
        h = ab * h + ((dtv) * (Bv)) * (uv);        \
        float y_ = (Cv) * h;                       \
        y_ += __shfl_xor(y_, 1);                   \
        y_ += __shfl_xor(y_, 2);                   \
        y_ += __shfl_xor(y_, 4);                   \
        y_ += __shfl_xor(y_, 8);                   \
        yy = y_; }

#pragma unroll 1
    for (int tg = 0; tg < CLEN; tg += 8) {
        float4 d0 = *(const float4*)(dtp + tg);  float4 d1 = *(const float4*)(dtp + tg + 4);
        float4 u0 = *(const float4*)(up + tg);   float4 u1 = *(const float4*)(up + tg + 4);
        float4 B0 = *(const float4*)(Bp + tg);   float4 B1 = *(const float4*)(Bp + tg + 4);
        float4 C0 = *(const float4*)(Cp + tg);   float4 C1 = *(const float4*)(Cp + tg + 4);
        float4 z0 = *(const float4*)(zp + tg);   float4 z1 = *(const float4*)(zp + tg + 4);

        float y0, y1, y2, y3, y4, y5, y6, y7;
        S3(d0.x, u0.x, B0.x, C0.x, y0)
        S3(d0.y, u0.y, B0.y, C0.y, y1)
        S3(d0.z, u0.z, B0.z, C0.z, y2)
        S3(d0.w, u0.w, B0.w, C0.w, y3)
        S3(d1.x, u1.x, B1.x, C1.x, y4)
        S3(d1.y, u1.y, B1.y, C1.y, y5)
        S3(d1.z, u1.z, B1.z, C1.z, y6)
        S3(d1.w, u1.w, B1.w, C1.w, y7)

        if (s == 0) {
            *(float4*)(gp + tg)     = make_float4(y0 * z0.x, y1 * z0.y, y2 * z0.z, y3 * z0.w);
            *(float4*)(gp + tg + 4) = make_float4(y4 * z1.x, y5 * z1.y, y6 * z1.z, y7 * z1.w);
        }
    }
#undef S3
}

// ---------------------------------------------------------------------------
// Workspace (floats), max extent 21,168,128:
//   xz      [0, 8388608)    then gated_t [0,4194304), P2_1 [4194304,6291456)
//   hend   [4194304, 4718592)   (NSCAN=524288 each — FIXED round-5 overlap bug)
//   prodA  [4718592, 5242880)
//   hstart [5242880, 5767168)   (scan phase only; P2_1 overwrites later)
//   A/B splits [8388608,17825792) -> dead after GEMM1
//   u_t [8388608,12582912), zs_t [12582912,16777216)
//   Pt [16777216,16973824), dtb_t [16973824,21168128)
//   G splits [8388608,14680064), Wo splits [14680064,17825792) after scan
// ---------------------------------------------------------------------------
extern "C" void kernel_launch(void* const* d_in, const int* in_sizes, int n_in,
                              void* d_out, int out_size, void* d_ws, size_t ws_size,
                              hipStream_t stream) {
    const float* inputs = (const float*)d_in[0];
    const float* W_in   = (const float*)d_in[1];
    const float* W_conv = (const float*)d_in[2];
    const float* b_conv = (const float*)d_in[3];
    const float* W_x    = (const float*)d_in[4];
    const float* W_dt   = (const float*)d_in[5];
    const float* b_dt   = (const float*)d_in[6];
    const float* A_log  = (const float*)d_in[7];
    const float* W_out  = (const float*)d_in[8];
    float* out = (float*)d_out;

    float* ws = (float*)d_ws;
    float* xz      = ws;
    float* gated_t = ws;
    float* P2_1    = ws + 4194304;
    float* hend    = ws + 4194304;            // 524288
    float* prodA   = ws + 4718592;            // 524288
    float* hstart  = ws + 5242880;            // 524288
    unsigned short* A1s = (unsigned short*)(ws + 8388608);
    unsigned short* A2s = (unsigned short*)(ws + 9437184);
    unsigned short* A3s = (unsigned short*)(ws + 10485760);
    unsigned short* B1s = (unsigned short*)(ws + 11534336);
    unsigned short* B2s = (unsigned short*)(ws + 13631488);
    unsigned short* B3s = (unsigned short*)(ws + 15728640);
    float* u_t     = ws + 8388608;
    float* zs_t    = ws + 12582912;
    float* Pt      = ws + 16777216;
    float* dtb_t   = ws + 16973824;
    unsigned short* G1s  = (unsigned short*)(ws + 8388608);
    unsigned short* G2s  = (unsigned short*)(ws + 10485760);
    unsigned short* G3s  = (unsigned short*)(ws + 12582912);
    unsigned short* Wo1s = (unsigned short*)(ws + 14680064);
    unsigned short* Wo2s = (unsigned short*)(ws + 15728640);
    unsigned short* Wo3s = (unsigned short*)(ws + 16777216);

    // 0) split inputs and W_in into bf16 triples
    split3<<<2048, 256, 0, stream>>>((const float4*)inputs, (ushort4*)A1s,
                                     (ushort4*)A2s, (ushort4*)A3s, 524288);
    split3<<<2048, 256, 0, stream>>>((const float4*)W_in, (ushort4*)B1s,
                                     (ushort4*)B2s, (ushort4*)B3s, 1048576);
    // 1) xz = inputs @ W_in^T via split-bf16 MFMA
    gemm_mfma_split<<<dim3(32, 16, 1), 256, 0, stream>>>(
        A1s, A2s, A3s, B1s, B2s, B3s, xz, xz, MROWS, 2 * DI, DD, DD);
    // 2) u_t, zs_t
    conv_silu_t<<<dim3(DI / CCC, LL / CTT, BB), 256, 0, stream>>>(xz, W_conv, b_conv, u_t, zs_t);
    // 3) Pt
    proj_gemm_t<<<dim3(MROWS / 16), 256, 0, stream>>>(u_t, W_x, Pt);
    // 4) dtb_t
    dt_gemm_t<<<dim3(DI / 256, MROWS / 16), 256, 0, stream>>>(Pt, W_dt, b_dt, dtb_t);
    // 5) chunked scan: part1 -> part2 -> part3 (gated_t in dead xz region)
    scan_part1<<<dim3(NSCAN / 256), 256, 0, stream>>>(
        dtb_t, u_t, Pt, A_log, hend, prodA);
    scan_part2<<<dim3(BB * DI * SS / 256), 256, 0, stream>>>(hend, prodA, hstart);
    scan_part3<<<dim3(NSCAN / 256), 256, 0, stream>>>(
        dtb_t, u_t, Pt, zs_t, A_log, hstart, gated_t);
    // 6) transpose+split gated, split W_out
    split3_t<<<dim3(32, 32), 256, 0, stream>>>(gated_t, G1s, G2s, G3s);
    split3<<<2048, 256, 0, stream>>>((const float4*)W_out, (ushort4*)Wo1s,
                                     (ushort4*)Wo2s, (ushort4*)Wo3s, 524288);
    // 7) out = gated @ W_out^T, split-K=2; then reduce
    gemm_mfma_split<<<dim3(8, 16, 2), 256, 0, stream>>>(
        G1s, G2s, G3s, Wo1s, Wo2s, Wo3s, out, P2_1, MROWS, DD, DI, DI / 2);
    reduce_add_inplace<<<1024, 256, 0, stream>>>((float4*)out, (const float4*)P2_1, 524288);
}

// Round 7
// 454.148 us; speedup vs baseline: 1.1581x; 1.1581x over previous
//
#include <hip/hip_runtime.h>
#include <hip/hip_bf16.h>

// Problem constants
#define BB 2
#define LL 1024
#define DD 1024
#define DI 2048
#define SS 16
#define KK 4
#define RR 64
#define MROWS (BB*LL)   // 2048
#define NCT 32          // t-chunks for scan
#define CTL 32          // steps per chunk (LL / NCT)

typedef __attribute__((ext_vector_type(8))) short short8;     // 8 bf16 = 4 VGPR
typedef __attribute__((ext_vector_type(4))) float floatx4;    // MFMA C/D

// RNE fp32 -> bf16 bits
__device__ __forceinline__ unsigned short f2bf(float v) {
    unsigned int u = __float_as_uint(v);
    return (unsigned short)((u + 0x7FFFu + ((u >> 16) & 1u)) >> 16);
}
__device__ __forceinline__ float bf2f(unsigned short h) {
    return __uint_as_float(((unsigned int)h) << 16);
}
__device__ __forceinline__ void split1(float v, unsigned short& a,
                                       unsigned short& b, unsigned short& c) {
    a = f2bf(v);
    float r = v - bf2f(a);
    b = f2bf(r);
    float r2 = r - bf2f(b);
    c = f2bf(r2);
}

// ---------------------------------------------------------------------------
// split3: fp32[n] -> three bf16[n] (hi, mid, lo), elementwise
// ---------------------------------------------------------------------------
__global__ __launch_bounds__(256) void split3(const float4* __restrict__ src,
                                              ushort4* __restrict__ d1,
                                              ushort4* __restrict__ d2,
                                              ushort4* __restrict__ d3, int n4) {
    for (int i = blockIdx.x * 256 + threadIdx.x; i < n4; i += gridDim.x * 256) {
        const float4 v = src[i];
        ushort4 o1, o2, o3;
        split1(v.x, o1.x, o2.x, o3.x);
        split1(v.y, o1.y, o2.y, o3.y);
        split1(v.z, o1.z, o2.z, o3.z);
        split1(v.w, o1.w, o2.w, o3.w);
        d1[i] = o1; d2[i] = o2; d3[i] = o3;
    }
}

// ---------------------------------------------------------------------------
// Split-bf16 MFMA GEMM (unchanged from round 4/6)
// ---------------------------------------------------------------------------
__global__ __launch_bounds__(256, 2) void gemm_mfma_split(
    const unsigned short* __restrict__ A1, const unsigned short* __restrict__ A2,
    const unsigned short* __restrict__ A3,
    const unsigned short* __restrict__ B1, const unsigned short* __restrict__ B2,
    const unsigned short* __restrict__ B3,
    float* __restrict__ C0, float* __restrict__ C1,
    int M, int N, int Kstride, int Klen) {
    __shared__ unsigned short As[3][128][40];
    __shared__ unsigned short Bs[3][128][40];
    const int tid = threadIdx.x;
    const int bm = blockIdx.y * 128;
    const int bn = blockIdx.x * 128;
    const int Koff = blockIdx.z * Klen;
    float* __restrict__ C = blockIdx.z ? C1 : C0;

    const int lane = tid & 63;
    const int wv = tid >> 6;
    const int lm = lane & 15;
    const int kq = lane >> 4;
    const int wm = (wv >> 1) * 64;
    const int wn = (wv & 1) * 64;

    floatx4 acc[4][4];
    const floatx4 zf = {0.f, 0.f, 0.f, 0.f};
#pragma unroll
    for (int i = 0; i < 4; ++i)
#pragma unroll
        for (int j = 0; j < 4; ++j) acc[i][j] = zf;

    const int ch0 = tid * 2;

    for (int kt = Koff; kt < Koff + Klen; kt += 32) {
#define STAGE(p, SRC_A, SRC_B)                                                          \
        {                                                                               \
            const int r0 = (ch0) >> 2, c0 = ((ch0) & 3) * 8;                            \
            const int r1 = (ch0 + 1) >> 2, c1 = ((ch0 + 1) & 3) * 8;                    \
            *(short8*)&As[p][r0][c0] = *(const short8*)&SRC_A[(size_t)(bm + r0) * Kstride + kt + c0]; \
            *(short8*)&As[p][r1][c1] = *(const short8*)&SRC_A[(size_t)(bm + r1) * Kstride + kt + c1]; \
            *(short8*)&Bs[p][r0][c0] = *(const short8*)&SRC_B[(size_t)(bn + r0) * Kstride + kt + c0]; \
            *(short8*)&Bs[p][r1][c1] = *(const short8*)&SRC_B[(size_t)(bn + r1) * Kstride + kt + c1]; \
        }
        STAGE(0, A1, B1)
        STAGE(1, A2, B2)
        STAGE(2, A3, B3)
#undef STAGE
        __syncthreads();

        short8 af[3][4];
#pragma unroll
        for (int p = 0; p < 3; ++p)
#pragma unroll
            for (int i = 0; i < 4; ++i)
                af[p][i] = *(const short8*)&As[p][wm + i * 16 + lm][kq * 8];

#define PROD(p, bfq)                                                                     \
        _Pragma("unroll")                                                                \
        for (int i = 0; i < 4; ++i)                                                      \
            _Pragma("unroll")                                                            \
            for (int j = 0; j < 4; ++j)                                                  \
                acc[i][j] = __builtin_amdgcn_mfma_f32_16x16x32_bf16(af[p][i], bfq[j],    \
                                                                    acc[i][j], 0, 0, 0);
        {
            short8 bfq[4];
#pragma unroll
            for (int j = 0; j < 4; ++j) bfq[j] = *(const short8*)&Bs[0][wn + j * 16 + lm][kq * 8];
            PROD(0, bfq)
            PROD(1, bfq)
            PROD(2, bfq)
        }
        {
            short8 bfq[4];
#pragma unroll
            for (int j = 0; j < 4; ++j) bfq[j] = *(const short8*)&Bs[1][wn + j * 16 + lm][kq * 8];
            PROD(0, bfq)
            PROD(1, bfq)
        }
        {
            short8 bfq[4];
#pragma unroll
            for (int j = 0; j < 4; ++j) bfq[j] = *(const short8*)&Bs[2][wn + j * 16 + lm][kq * 8];
            PROD(0, bfq)
        }
#undef PROD
        __syncthreads();
    }

#pragma unroll
    for (int i = 0; i < 4; ++i) {
        const int mrow = bm + wm + i * 16 + kq * 4;
#pragma unroll
        for (int j = 0; j < 4; ++j) {
            const int col = bn + wn + j * 16 + lm;
#pragma unroll
            for (int r = 0; r < 4; ++r)
                C[(size_t)(mrow + r) * N + col] = acc[i][j][r];
        }
    }
}

// ---------------------------------------------------------------------------
__global__ __launch_bounds__(256) void reduce_add_inplace(float4* __restrict__ dst,
                                                          const float4* __restrict__ src,
                                                          int n4) {
    for (int i = blockIdx.x * 256 + threadIdx.x; i < n4; i += gridDim.x * 256) {
        float4 a = dst[i];
        const float4 b = src[i];
        a.x += b.x; a.y += b.y; a.z += b.z; a.w += b.w;
        dst[i] = a;
    }
}

// ---------------------------------------------------------------------------
// Depthwise causal conv (K=4) + bias + silu, ROW-MAJOR outputs:
//   u[(b*L+t)*DI + c] = silu(conv(x)+b);  zs[...] = silu(z)
// (round-1 structure, verified). All loads/stores coalesced over c.
// ---------------------------------------------------------------------------
__global__ __launch_bounds__(256) void conv_silu_rm(const float* __restrict__ xz,
                                                    const float* __restrict__ Wc,
                                                    const float* __restrict__ bc,
                                                    float* __restrict__ u,
                                                    float* __restrict__ zs) {
    const int c = blockIdx.x * 256 + threadIdx.x;
    const int t = blockIdx.y;
    const int b = blockIdx.z;
    const float* xcol = xz + (size_t)b * LL * (2 * DI) + c;
    const float w0 = Wc[c * 4 + 0], w1 = Wc[c * 4 + 1];
    const float w2 = Wc[c * 4 + 2], w3 = Wc[c * 4 + 3];
    float acc = bc[c];
    if (t >= 3) acc += xcol[(size_t)(t - 3) * (2 * DI)] * w0;
    if (t >= 2) acc += xcol[(size_t)(t - 2) * (2 * DI)] * w1;
    if (t >= 1) acc += xcol[(size_t)(t - 1) * (2 * DI)] * w2;
    acc += xcol[(size_t)t * (2 * DI)] * w3;
    const float zv = xcol[(size_t)t * (2 * DI) + DI];
    const size_t o = ((size_t)b * LL + t) * DI + c;
    u[o]  = acc / (1.f + __expf(-acc));
    zs[o] = zv / (1.f + __expf(-zv));
}

// ---------------------------------------------------------------------------
// proj: P[m][96] = u[m][:] @ W_x^T   (row-major output; round-1 structure)
// ---------------------------------------------------------------------------
__global__ __launch_bounds__(256) void proj_gemm(const float* __restrict__ U,
                                                 const float* __restrict__ Wx,
                                                 float* __restrict__ P) {
    const int BKp = 64;
    __shared__ float Us[16][BKp + 1];
    __shared__ float Ws[96][BKp + 1];
    const int tid = threadIdx.x;
    const int m0 = blockIdx.x * 16;
    const int tx = tid & 31;
    const int ty = tid >> 5;
    float acc[2][3] = {{0.f, 0.f, 0.f}, {0.f, 0.f, 0.f}};

    for (int kt = 0; kt < DI; kt += BKp) {
        {
            const int r = tid >> 4;
            const int c4 = (tid & 15) << 2;
            float4 v = *(const float4*)&U[(size_t)(m0 + r) * DI + kt + c4];
            Us[r][c4] = v.x; Us[r][c4 + 1] = v.y; Us[r][c4 + 2] = v.z; Us[r][c4 + 3] = v.w;
        }
#pragma unroll
        for (int i = 0; i < 6; ++i) {
            const int idx = tid + i * 256;
            const int r = idx >> 4;
            const int c4 = (idx & 15) << 2;
            float4 v = *(const float4*)&Wx[(size_t)r * DI + kt + c4];
            Ws[r][c4] = v.x; Ws[r][c4 + 1] = v.y; Ws[r][c4 + 2] = v.z; Ws[r][c4 + 3] = v.w;
        }
        __syncthreads();
#pragma unroll 8
        for (int k = 0; k < BKp; ++k) {
            const float um0 = Us[ty * 2][k];
            const float um1 = Us[ty * 2 + 1][k];
#pragma unroll
            for (int j = 0; j < 3; ++j) {
                const float w = Ws[tx + 32 * j][k];
                acc[0][j] += um0 * w;
                acc[1][j] += um1 * w;
            }
        }
        __syncthreads();
    }
#pragma unroll
    for (int i = 0; i < 2; ++i)
#pragma unroll
        for (int j = 0; j < 3; ++j)
            P[(size_t)(m0 + ty * 2 + i) * 96 + tx + 32 * j] = acc[i][j];
}

// ---------------------------------------------------------------------------
// dt[m][c] = softplus(P[m][:64] @ W_dt^T + b_dt)  (row-major; round-1 structure)
// ---------------------------------------------------------------------------
__global__ __launch_bounds__(256) void dt_gemm(const float* __restrict__ P,
                                               const float* __restrict__ Wdt,
                                               const float* __restrict__ bdt,
                                               float* __restrict__ dtb) {
    __shared__ float ps[16][68];
    const int tid = threadIdx.x;
    const int c = blockIdx.x * 256 + tid;
    const int m0 = blockIdx.y * 16;
    {
        const int r = tid >> 4;
        const int c4 = (tid & 15) << 2;
        float4 v = *(const float4*)&P[(size_t)(m0 + r) * 96 + c4];
        ps[r][c4] = v.x; ps[r][c4 + 1] = v.y; ps[r][c4 + 2] = v.z; ps[r][c4 + 3] = v.w;
    }
    float w[64];
#pragma unroll
    for (int r4 = 0; r4 < 64; r4 += 4) {
        float4 v = *(const float4*)&Wdt[(size_t)c * 64 + r4];
        w[r4] = v.x; w[r4 + 1] = v.y; w[r4 + 2] = v.z; w[r4 + 3] = v.w;
    }
    const float bd = bdt[c];
    __syncthreads();
#pragma unroll 4
    for (int m = 0; m < 16; ++m) {
        float acc = bd;
#pragma unroll
        for (int r4 = 0; r4 < 64; r4 += 4) {
            float4 p = *(const float4*)&ps[m][r4];
            acc += p.x * w[r4] + p.y * w[r4 + 1] + p.z * w[r4 + 2] + p.w * w[r4 + 3];
        }
        const float sp = (acc > 20.f) ? acc : __logf(1.f + __expf(acc));
        dtb[(size_t)(m0 + m) * DI + c] = sp;
    }
}

// ---------------------------------------------------------------------------
// Transposed chunked scan.  Lane = (b, c, chunk); h[16] states in registers.
// B/C are wave-uniform scalar loads from P rows; u/dt/z coalesced over c.
// Pass 1: local scan from h=0; store h_end[16] and sum_dt.
//   hend layout: [((b*NCT+ch)*DI + c)*16 + s]
// ---------------------------------------------------------------------------
__global__ __launch_bounds__(256) void tscan1(const float* __restrict__ dtb,
                                              const float* __restrict__ u,
                                              const float* __restrict__ P,
                                              const float* __restrict__ A_log,
                                              float* __restrict__ hend,
                                              float* __restrict__ sumdt) {
    const int c = blockIdx.x * 256 + threadIdx.x;
    const int ch = blockIdx.y;
    const int b = blockIdx.z;

    float A[16];
#pragma unroll
    for (int s4 = 0; s4 < 16; s4 += 4) {
        float4 v = *(const float4*)&A_log[c * 16 + s4];
        A[s4] = -__expf(v.x); A[s4 + 1] = -__expf(v.y);
        A[s4 + 2] = -__expf(v.z); A[s4 + 3] = -__expf(v.w);
    }
    float h[16];
#pragma unroll
    for (int s = 0; s < 16; ++s) h[s] = 0.f;
    float sd = 0.f;

    const size_t m0 = (size_t)b * LL + (size_t)ch * CTL;
#pragma unroll 2
    for (int t = 0; t < CTL; ++t) {
        const size_t m = m0 + t;
        const float dt = dtb[m * DI + c];
        const float uv = u[m * DI + c];
        const float dtu = dt * uv;
        sd += dt;
        const float* __restrict__ bc = P + m * 96 + 64;   // wave-uniform
#pragma unroll
        for (int s = 0; s < 16; ++s) {
            const float ab = __expf(dt * A[s]);
            h[s] = ab * h[s] + bc[s] * dtu;
        }
    }
    const size_t o = (((size_t)b * NCT + ch) * DI + c) * 16;
#pragma unroll
    for (int s4 = 0; s4 < 16; s4 += 4)
        *(float4*)&hend[o + s4] = make_float4(h[s4], h[s4 + 1], h[s4 + 2], h[s4 + 3]);
    sumdt[((size_t)b * NCT + ch) * DI + c] = sd;
}

// ---------------------------------------------------------------------------
// Pass 2: combine chunks in place: hend[ch] becomes h_start[ch].
// Lane = (b, c, s).  decay over a chunk = exp(A * sum_dt)  (exact product).
// ---------------------------------------------------------------------------
__global__ __launch_bounds__(256) void tscan2(float* __restrict__ hend,
                                              const float* __restrict__ sumdt,
                                              const float* __restrict__ A_log) {
    const int id = blockIdx.x * 256 + threadIdx.x;
    const int s = id & 15;
    const int c = (id >> 4) & (DI - 1);
    const int b = id >> 15;
    const float Aval = -__expf(A_log[c * 16 + s]);
    float hs = 0.f;
#pragma unroll 1
    for (int ch = 0; ch < NCT; ++ch) {
        const size_t base = ((size_t)b * NCT + ch) * DI + c;
        const float he = hend[base * 16 + s];
        const float sd = sumdt[base];
        hend[base * 16 + s] = hs;
        hs = __expf(Aval * sd) * hs + he;
    }
}

// ---------------------------------------------------------------------------
// Pass 3: re-run from h_start, compute y = sum_s C[s]*h[s], gate with silu(z).
// ---------------------------------------------------------------------------
__global__ __launch_bounds__(256) void tscan3(const float* __restrict__ dtb,
                                              const float* __restrict__ u,
                                              const float* __restrict__ P,
                                              const float* __restrict__ zs,
                                              const float* __restrict__ A_log,
                                              const float* __restrict__ hstart,
                                              float* __restrict__ gated) {
    const int c = blockIdx.x * 256 + threadIdx.x;
    const int ch = blockIdx.y;
    const int b = blockIdx.z;

    float A[16];
#pragma unroll
    for (int s4 = 0; s4 < 16; s4 += 4) {
        float4 v = *(const float4*)&A_log[c * 16 + s4];
        A[s4] = -__expf(v.x); A[s4 + 1] = -__expf(v.y);
        A[s4 + 2] = -__expf(v.z); A[s4 + 3] = -__expf(v.w);
    }
    float h[16];
    const size_t o = (((size_t)b * NCT + ch) * DI + c) * 16;
#pragma unroll
    for (int s4 = 0; s4 < 16; s4 += 4) {
        float4 v = *(const float4*)&hstart[o + s4];
        h[s4] = v.x; h[s4 + 1] = v.y; h[s4 + 2] = v.z; h[s4 + 3] = v.w;
    }

    const size_t m0 = (size_t)b * LL + (size_t)ch * CTL;
#pragma unroll 2
    for (int t = 0; t < CTL; ++t) {
        const size_t m = m0 + t;
        const float dt = dtb[m * DI + c];
        const float uv = u[m * DI + c];
        const float dtu = dt * uv;
        const float* __restrict__ bc = P + m * 96 + 64;   // wave-uniform B then C
        float y = 0.f;
#pragma unroll
        for (int s = 0; s < 16; ++s) {
            const float ab = __expf(dt * A[s]);
            h[s] = ab * h[s] + bc[s] * dtu;
            y += bc[16 + s] * h[s];
        }
        const float zv = zs[m * DI + c];
        gated[m * DI + c] = y * zv;
    }
}

// ---------------------------------------------------------------------------
// Workspace (floats), max extent 21,168,128 (proven footprint):
//   xz [0, 8388608)            (dead after conv)
//   gated [0, 4194304)         (pass3 output, row-major [M][DI])
//   hend [4194304, 6291456)    sumdt [6291456, 6356992)    (scan phase)
//   P2_1 [4194304, 6291456)    (GEMM2 partial; after scan)
//   GEMM1 splits: A1s@8388608 A2s@9437184 A3s@10485760 (1.05M fl each)
//                 B1s@11534336 B2s@13631488 B3s@15728640 (2.1M fl each) -> dead
//   u [8388608, 12582912), zs [12582912, 16777216)   (after GEMM1)
//   P [16777216, 16973824), dtb [16973824, 21168128)
//   G1s@8388608 G2s@10485760 G3s@12582912 (2.1M fl each)   (after pass3)
//   Wo1s@14680064 Wo2s@15728640 Wo3s@16777216 (1.05M fl each)
// ---------------------------------------------------------------------------
extern "C" void kernel_launch(void* const* d_in, const int* in_sizes, int n_in,
                              void* d_out, int out_size, void* d_ws, size_t ws_size,
                              hipStream_t stream) {
    const float* inputs = (const float*)d_in[0];
    const float* W_in   = (const float*)d_in[1];
    const float* W_conv = (const float*)d_in[2];
    const float* b_conv = (const float*)d_in[3];
    const float* W_x    = (const float*)d_in[4];
    const float* W_dt   = (const float*)d_in[5];
    const float* b_dt   = (const float*)d_in[6];
    const float* A_log  = (const float*)d_in[7];
    const float* W_out  = (const float*)d_in[8];
    float* out = (float*)d_out;

    float* ws = (float*)d_ws;
    float* xz      = ws;
    float* gated   = ws;
    float* hend    = ws + 4194304;            // 2097152
    float* sumdt   = ws + 6291456;            // 65536
    float* P2_1    = ws + 4194304;            // after scan
    unsigned short* A1s = (unsigned short*)(ws + 8388608);
    unsigned short* A2s = (unsigned short*)(ws + 9437184);
    unsigned short* A3s = (unsigned short*)(ws + 10485760);
    unsigned short* B1s = (unsigned short*)(ws + 11534336);
    unsigned short* B2s = (unsigned short*)(ws + 13631488);
    unsigned short* B3s = (unsigned short*)(ws + 15728640);
    float* u       = ws + 8388608;
    float* zs      = ws + 12582912;
    float* P       = ws + 16777216;
    float* dtb     = ws + 16973824;
    unsigned short* G1s  = (unsigned short*)(ws + 8388608);
    unsigned short* G2s  = (unsigned short*)(ws + 10485760);
    unsigned short* G3s  = (unsigned short*)(ws + 12582912);
    unsigned short* Wo1s = (unsigned short*)(ws + 14680064);
    unsigned short* Wo2s = (unsigned short*)(ws + 15728640);
    unsigned short* Wo3s = (unsigned short*)(ws + 16777216);

    // 0) split inputs and W_in into bf16 triples
    split3<<<2048, 256, 0, stream>>>((const float4*)inputs, (ushort4*)A1s,
                                     (ushort4*)A2s, (ushort4*)A3s, 524288);
    split3<<<2048, 256, 0, stream>>>((const float4*)W_in, (ushort4*)B1s,
                                     (ushort4*)B2s, (ushort4*)B3s, 1048576);
    // 1) xz = inputs @ W_in^T via split-bf16 MFMA
    gemm_mfma_split<<<dim3(32, 16, 1), 256, 0, stream>>>(
        A1s, A2s, A3s, B1s, B2s, B3s, xz, xz, MROWS, 2 * DI, DD, DD);
    // 2) u, zs row-major (overwrites dead A/B splits)
    conv_silu_rm<<<dim3(DI / 256, LL, BB), 256, 0, stream>>>(xz, W_conv, b_conv, u, zs);
    // 3) P[m][96]
    proj_gemm<<<dim3(MROWS / 16), 256, 0, stream>>>(u, W_x, P);
    // 4) dtb[m][DI]
    dt_gemm<<<dim3(DI / 256, MROWS / 16), 256, 0, stream>>>(P, W_dt, b_dt, dtb);
    // 5) transposed chunked scan -> gated[m][DI] (in dead xz region)
    tscan1<<<dim3(DI / 256, NCT, BB), 256, 0, stream>>>(dtb, u, P, A_log, hend, sumdt);
    tscan2<<<dim3(BB * DI * SS / 256), 256, 0, stream>>>(hend, sumdt, A_log);
    tscan3<<<dim3(DI / 256, NCT, BB), 256, 0, stream>>>(dtb, u, P, zs, A_log, hend, gated);
    // 6) split gated (already [M][K] row-major) and W_out
    split3<<<2048, 256, 0, stream>>>((const float4*)gated, (ushort4*)G1s,
                                     (ushort4*)G2s, (ushort4*)G3s, 1048576);
    split3<<<2048, 256, 0, stream>>>((const float4*)W_out, (ushort4*)Wo1s,
                                     (ushort4*)Wo2s, (ushort4*)Wo3s, 524288);
    // 7) out = gated @ W_out^T, split-K=2; then reduce
    gemm_mfma_split<<<dim3(8, 16, 2), 256, 0, stream>>>(
        G1s, G2s, G3s, Wo1s, Wo2s, Wo3s, out, P2_1, MROWS, DD, DI, DI / 2);
    reduce_add_inplace<<<1024, 256, 0, stream>>>((float4*)out, (const float4*)P2_1, 524288);
}

// Round 8
// 411.840 us; speedup vs baseline: 1.2771x; 1.1027x over previous
//
#include <hip/hip_runtime.h>
#include <hip/hip_bf16.h>

// Problem constants
#define BB 2
#define LL 1024
#define DD 1024
#define DI 2048
#define SS 16
#define KK 4
#define RR 64
#define MROWS (BB*LL)   // 2048
#define NCT 32          // t-chunks for scan
#define CTL 32          // steps per chunk (LL / NCT)

typedef __attribute__((ext_vector_type(8))) short short8;     // 8 bf16 = 4 VGPR
typedef __attribute__((ext_vector_type(4))) float floatx4;    // MFMA C/D

// RNE fp32 -> bf16 bits
__device__ __forceinline__ unsigned short f2bf(float v) {
    unsigned int u = __float_as_uint(v);
    return (unsigned short)((u + 0x7FFFu + ((u >> 16) & 1u)) >> 16);
}
__device__ __forceinline__ float bf2f(unsigned short h) {
    return __uint_as_float(((unsigned int)h) << 16);
}
__device__ __forceinline__ void split1(float v, unsigned short& a,
                                       unsigned short& b, unsigned short& c) {
    a = f2bf(v);
    float r = v - bf2f(a);
    b = f2bf(r);
    float r2 = r - bf2f(b);
    c = f2bf(r2);
}

// ---------------------------------------------------------------------------
// split3: fp32[n] -> three bf16[n] (hi, mid, lo), elementwise
// ---------------------------------------------------------------------------
__global__ __launch_bounds__(256) void split3(const float4* __restrict__ src,
                                              ushort4* __restrict__ d1,
                                              ushort4* __restrict__ d2,
                                              ushort4* __restrict__ d3, int n4) {
    for (int i = blockIdx.x * 256 + threadIdx.x; i < n4; i += gridDim.x * 256) {
        const float4 v = src[i];
        ushort4 o1, o2, o3;
        split1(v.x, o1.x, o2.x, o3.x);
        split1(v.y, o1.y, o2.y, o3.y);
        split1(v.z, o1.z, o2.z, o3.z);
        split1(v.w, o1.w, o2.w, o3.w);
        d1[i] = o1; d2[i] = o2; d3[i] = o3;
    }
}

// ---------------------------------------------------------------------------
// Split-bf16 MFMA GEMM, 2-phase LDS (40 KB): slot0 = split1 (resident),
// slot1 = split2 then split3.  Products {11,21,12,22} in phase A,
// {31,13} in phase B using register-resident af0/bf0 fragments.
// 128x128 tile, BK=32, 256 threads = 4 waves, 3 blocks/CU.
// ---------------------------------------------------------------------------
__global__ __launch_bounds__(256, 3) void gemm_mfma_split(
    const unsigned short* __restrict__ A1, const unsigned short* __restrict__ A2,
    const unsigned short* __restrict__ A3,
    const unsigned short* __restrict__ B1, const unsigned short* __restrict__ B2,
    const unsigned short* __restrict__ B3,
    float* __restrict__ C0, float* __restrict__ C1,
    int M, int N, int Kstride, int Klen) {
    __shared__ unsigned short As[2][128][40];   // [slot][m][k], pad 32->40
    __shared__ unsigned short Bs[2][128][40];
    const int tid = threadIdx.x;
    const int bm = blockIdx.y * 128;
    const int bn = blockIdx.x * 128;
    const int Koff = blockIdx.z * Klen;
    float* __restrict__ C = blockIdx.z ? C1 : C0;

    const int lane = tid & 63;
    const int wv = tid >> 6;
    const int lm = lane & 15;
    const int kq = lane >> 4;
    const int wm = (wv >> 1) * 64;
    const int wn = (wv & 1) * 64;

    floatx4 acc[4][4];
    const floatx4 zf = {0.f, 0.f, 0.f, 0.f};
#pragma unroll
    for (int i = 0; i < 4; ++i)
#pragma unroll
        for (int j = 0; j < 4; ++j) acc[i][j] = zf;

    const int ch0 = tid * 2;
    const int r0 = ch0 >> 2, cc0 = (ch0 & 3) * 8;
    const int r1 = (ch0 + 1) >> 2, cc1 = ((ch0 + 1) & 3) * 8;

#define PROD(afq, bfq)                                                                   \
        _Pragma("unroll")                                                                \
        for (int i = 0; i < 4; ++i)                                                      \
            _Pragma("unroll")                                                            \
            for (int j = 0; j < 4; ++j)                                                  \
                acc[i][j] = __builtin_amdgcn_mfma_f32_16x16x32_bf16(afq[i], bfq[j],      \
                                                                    acc[i][j], 0, 0, 0);

    for (int kt = Koff; kt < Koff + Klen; kt += 32) {
        // ---- phase A staging: splits 1,2
        *(short8*)&As[0][r0][cc0] = *(const short8*)&A1[(size_t)(bm + r0) * Kstride + kt + cc0];
        *(short8*)&As[0][r1][cc1] = *(const short8*)&A1[(size_t)(bm + r1) * Kstride + kt + cc1];
        *(short8*)&As[1][r0][cc0] = *(const short8*)&A2[(size_t)(bm + r0) * Kstride + kt + cc0];
        *(short8*)&As[1][r1][cc1] = *(const short8*)&A2[(size_t)(bm + r1) * Kstride + kt + cc1];
        *(short8*)&Bs[0][r0][cc0] = *(const short8*)&B1[(size_t)(bn + r0) * Kstride + kt + cc0];
        *(short8*)&Bs[0][r1][cc1] = *(const short8*)&B1[(size_t)(bn + r1) * Kstride + kt + cc1];
        *(short8*)&Bs[1][r0][cc0] = *(const short8*)&B2[(size_t)(bn + r0) * Kstride + kt + cc0];
        *(short8*)&Bs[1][r1][cc1] = *(const short8*)&B2[(size_t)(bn + r1) * Kstride + kt + cc1];
        __syncthreads();

        short8 af0[4], af1[4], bf0[4], bf1[4];
#pragma unroll
        for (int i = 0; i < 4; ++i) {
            af0[i] = *(const short8*)&As[0][wm + i * 16 + lm][kq * 8];
            af1[i] = *(const short8*)&As[1][wm + i * 16 + lm][kq * 8];
            bf0[i] = *(const short8*)&Bs[0][wn + i * 16 + lm][kq * 8];
            bf1[i] = *(const short8*)&Bs[1][wn + i * 16 + lm][kq * 8];
        }
        PROD(af0, bf0)   // a1*b1
        PROD(af1, bf0)   // a2*b1
        PROD(af0, bf1)   // a1*b2
        PROD(af1, bf1)   // a2*b2
        __syncthreads();

        // ---- phase B staging: split 3 overwrites slot 1
        *(short8*)&As[1][r0][cc0] = *(const short8*)&A3[(size_t)(bm + r0) * Kstride + kt + cc0];
        *(short8*)&As[1][r1][cc1] = *(const short8*)&A3[(size_t)(bm + r1) * Kstride + kt + cc1];
        *(short8*)&Bs[1][r0][cc0] = *(const short8*)&B3[(size_t)(bn + r0) * Kstride + kt + cc0];
        *(short8*)&Bs[1][r1][cc1] = *(const short8*)&B3[(size_t)(bn + r1) * Kstride + kt + cc1];
        __syncthreads();

        short8 af2[4], bf2[4];
#pragma unroll
        for (int i = 0; i < 4; ++i) {
            af2[i] = *(const short8*)&As[1][wm + i * 16 + lm][kq * 8];
            bf2[i] = *(const short8*)&Bs[1][wn + i * 16 + lm][kq * 8];
        }
        PROD(af2, bf0)   // a3*b1
        PROD(af0, bf2)   // a1*b3
        __syncthreads();
    }
#undef PROD

#pragma unroll
    for (int i = 0; i < 4; ++i) {
        const int mrow = bm + wm + i * 16 + kq * 4;
#pragma unroll
        for (int j = 0; j < 4; ++j) {
            const int col = bn + wn + j * 16 + lm;
#pragma unroll
            for (int r = 0; r < 4; ++r)
                C[(size_t)(mrow + r) * N + col] = acc[i][j][r];
        }
    }
}

// ---------------------------------------------------------------------------
__global__ __launch_bounds__(256) void reduce_add_inplace(float4* __restrict__ dst,
                                                          const float4* __restrict__ src,
                                                          int n4) {
    for (int i = blockIdx.x * 256 + threadIdx.x; i < n4; i += gridDim.x * 256) {
        float4 a = dst[i];
        const float4 b = src[i];
        a.x += b.x; a.y += b.y; a.z += b.z; a.w += b.w;
        dst[i] = a;
    }
}

// ---------------------------------------------------------------------------
// Depthwise causal conv (K=4) + bias + silu, row-major outputs (unchanged)
// ---------------------------------------------------------------------------
__global__ __launch_bounds__(256) void conv_silu_rm(const float* __restrict__ xz,
                                                    const float* __restrict__ Wc,
                                                    const float* __restrict__ bc,
                                                    float* __restrict__ u,
                                                    float* __restrict__ zs) {
    const int c = blockIdx.x * 256 + threadIdx.x;
    const int t = blockIdx.y;
    const int b = blockIdx.z;
    const float* xcol = xz + (size_t)b * LL * (2 * DI) + c;
    const float w0 = Wc[c * 4 + 0], w1 = Wc[c * 4 + 1];
    const float w2 = Wc[c * 4 + 2], w3 = Wc[c * 4 + 3];
    float acc = bc[c];
    if (t >= 3) acc += xcol[(size_t)(t - 3) * (2 * DI)] * w0;
    if (t >= 2) acc += xcol[(size_t)(t - 2) * (2 * DI)] * w1;
    if (t >= 1) acc += xcol[(size_t)(t - 1) * (2 * DI)] * w2;
    acc += xcol[(size_t)t * (2 * DI)] * w3;
    const float zv = xcol[(size_t)t * (2 * DI) + DI];
    const size_t o = ((size_t)b * LL + t) * DI + c;
    u[o]  = acc / (1.f + __expf(-acc));
    zs[o] = zv / (1.f + __expf(-zv));
}

// ---------------------------------------------------------------------------
// proj split-K=4: Pp[kz][m][96] = u[m][kz-window] @ W_x^T  (512 blocks)
// ---------------------------------------------------------------------------
__global__ __launch_bounds__(256) void proj_gemm_sk(const float* __restrict__ U,
                                                    const float* __restrict__ Wx,
                                                    float* __restrict__ Pp) {
    const int BKp = 64;
    __shared__ float Us[16][BKp + 1];
    __shared__ float Ws[96][BKp + 1];
    const int tid = threadIdx.x;
    const int m0 = blockIdx.x * 16;
    const int Koff = blockIdx.y * (DI / 4);
    float* __restrict__ P = Pp + (size_t)blockIdx.y * MROWS * 96;
    const int tx = tid & 31;
    const int ty = tid >> 5;
    float acc[2][3] = {{0.f, 0.f, 0.f}, {0.f, 0.f, 0.f}};

    for (int kt = Koff; kt < Koff + DI / 4; kt += BKp) {
        {
            const int r = tid >> 4;
            const int c4 = (tid & 15) << 2;
            float4 v = *(const float4*)&U[(size_t)(m0 + r) * DI + kt + c4];
            Us[r][c4] = v.x; Us[r][c4 + 1] = v.y; Us[r][c4 + 2] = v.z; Us[r][c4 + 3] = v.w;
        }
#pragma unroll
        for (int i = 0; i < 6; ++i) {
            const int idx = tid + i * 256;
            const int r = idx >> 4;
            const int c4 = (idx & 15) << 2;
            float4 v = *(const float4*)&Wx[(size_t)r * DI + kt + c4];
            Ws[r][c4] = v.x; Ws[r][c4 + 1] = v.y; Ws[r][c4 + 2] = v.z; Ws[r][c4 + 3] = v.w;
        }
        __syncthreads();
#pragma unroll 8
        for (int k = 0; k < BKp; ++k) {
            const float um0 = Us[ty * 2][k];
            const float um1 = Us[ty * 2 + 1][k];
#pragma unroll
            for (int j = 0; j < 3; ++j) {
                const float w = Ws[tx + 32 * j][k];
                acc[0][j] += um0 * w;
                acc[1][j] += um1 * w;
            }
        }
        __syncthreads();
    }
#pragma unroll
    for (int i = 0; i < 2; ++i)
#pragma unroll
        for (int j = 0; j < 3; ++j)
            P[(size_t)(m0 + ty * 2 + i) * 96 + tx + 32 * j] = acc[i][j];
}

// ---------------------------------------------------------------------------
// proj reduce: P[i] = sum_{kz<4} Pp[kz][i]
// ---------------------------------------------------------------------------
__global__ __launch_bounds__(256) void proj_reduce(float4* __restrict__ P,
                                                   const float4* __restrict__ Pp,
                                                   int n4) {
    for (int i = blockIdx.x * 256 + threadIdx.x; i < n4; i += gridDim.x * 256) {
        const float4 a = Pp[i];
        const float4 b = Pp[i + (size_t)n4];
        const float4 c = Pp[i + (size_t)2 * n4];
        const float4 d = Pp[i + (size_t)3 * n4];
        P[i] = make_float4(a.x + b.x + c.x + d.x, a.y + b.y + c.y + d.y,
                           a.z + b.z + c.z + d.z, a.w + b.w + c.w + d.w);
    }
}

// ---------------------------------------------------------------------------
// dt[m][c] = softplus(P[m][:64] @ W_dt^T + b_dt)  (unchanged)
// ---------------------------------------------------------------------------
__global__ __launch_bounds__(256) void dt_gemm(const float* __restrict__ P,
                                               const float* __restrict__ Wdt,
                                               const float* __restrict__ bdt,
                                               float* __restrict__ dtb) {
    __shared__ float ps[16][68];
    const int tid = threadIdx.x;
    const int c = blockIdx.x * 256 + tid;
    const int m0 = blockIdx.y * 16;
    {
        const int r = tid >> 4;
        const int c4 = (tid & 15) << 2;
        float4 v = *(const float4*)&P[(size_t)(m0 + r) * 96 + c4];
        ps[r][c4] = v.x; ps[r][c4 + 1] = v.y; ps[r][c4 + 2] = v.z; ps[r][c4 + 3] = v.w;
    }
    float w[64];
#pragma unroll
    for (int r4 = 0; r4 < 64; r4 += 4) {
        float4 v = *(const float4*)&Wdt[(size_t)c * 64 + r4];
        w[r4] = v.x; w[r4 + 1] = v.y; w[r4 + 2] = v.z; w[r4 + 3] = v.w;
    }
    const float bd = bdt[c];
    __syncthreads();
#pragma unroll 4
    for (int m = 0; m < 16; ++m) {
        float acc = bd;
#pragma unroll
        for (int r4 = 0; r4 < 64; r4 += 4) {
            float4 p = *(const float4*)&ps[m][r4];
            acc += p.x * w[r4] + p.y * w[r4 + 1] + p.z * w[r4 + 2] + p.w * w[r4 + 3];
        }
        const float sp = (acc > 20.f) ? acc : __logf(1.f + __expf(acc));
        dtb[(size_t)(m0 + m) * DI + c] = sp;
    }
}

// ---------------------------------------------------------------------------
// Transposed chunked scan (round-7 structure).  Lane = (b, c, chunk).
// ---------------------------------------------------------------------------
__global__ __launch_bounds__(256) void tscan1(const float* __restrict__ dtb,
                                              const float* __restrict__ u,
                                              const float* __restrict__ P,
                                              const float* __restrict__ A_log,
                                              float* __restrict__ hend,
                                              float* __restrict__ sumdt) {
    const int c = blockIdx.x * 256 + threadIdx.x;
    const int ch = blockIdx.y;
    const int b = blockIdx.z;

    float A[16];
#pragma unroll
    for (int s4 = 0; s4 < 16; s4 += 4) {
        float4 v = *(const float4*)&A_log[c * 16 + s4];
        A[s4] = -__expf(v.x); A[s4 + 1] = -__expf(v.y);
        A[s4 + 2] = -__expf(v.z); A[s4 + 3] = -__expf(v.w);
    }
    float h[16];
#pragma unroll
    for (int s = 0; s < 16; ++s) h[s] = 0.f;
    float sd = 0.f;

    const size_t m0 = (size_t)b * LL + (size_t)ch * CTL;
#pragma unroll 2
    for (int t = 0; t < CTL; ++t) {
        const size_t m = m0 + t;
        const float dt = dtb[m * DI + c];
        const float uv = u[m * DI + c];
        const float dtu = dt * uv;
        sd += dt;
        const float* __restrict__ bc = P + m * 96 + 64;   // wave-uniform
#pragma unroll
        for (int s = 0; s < 16; ++s) {
            const float ab = __expf(dt * A[s]);
            h[s] = ab * h[s] + bc[s] * dtu;
        }
    }
    const size_t o = (((size_t)b * NCT + ch) * DI + c) * 16;
#pragma unroll
    for (int s4 = 0; s4 < 16; s4 += 4)
        *(float4*)&hend[o + s4] = make_float4(h[s4], h[s4 + 1], h[s4 + 2], h[s4 + 3]);
    sumdt[((size_t)b * NCT + ch) * DI + c] = sd;
}

// ---------------------------------------------------------------------------
// Pass 2: combine chunks in place with batched prefetch (8-chunk groups).
// ---------------------------------------------------------------------------
__global__ __launch_bounds__(256) void tscan2(float* __restrict__ hend,
                                              const float* __restrict__ sumdt,
                                              const float* __restrict__ A_log) {
    const int id = blockIdx.x * 256 + threadIdx.x;
    const int s = id & 15;
    const int c = (id >> 4) & (DI - 1);
    const int b = id >> 15;
    const float Aval = -__expf(A_log[c * 16 + s]);
    float hs = 0.f;
#pragma unroll
    for (int g = 0; g < 4; ++g) {
        float he[8], sd[8];
#pragma unroll
        for (int j = 0; j < 8; ++j) {
            const size_t base = ((size_t)b * NCT + (g * 8 + j)) * DI + c;
            he[j] = hend[base * 16 + s];
            sd[j] = sumdt[base];
        }
#pragma unroll
        for (int j = 0; j < 8; ++j) {
            const size_t base = ((size_t)b * NCT + (g * 8 + j)) * DI + c;
            hend[base * 16 + s] = hs;
            hs = __expf(Aval * sd[j]) * hs + he[j];
        }
    }
}

// ---------------------------------------------------------------------------
// Pass 3: re-run from h_start, y = sum_s C[s]*h[s], gate with silu(z).
// ---------------------------------------------------------------------------
__global__ __launch_bounds__(256) void tscan3(const float* __restrict__ dtb,
                                              const float* __restrict__ u,
                                              const float* __restrict__ P,
                                              const float* __restrict__ zs,
                                              const float* __restrict__ A_log,
                                              const float* __restrict__ hstart,
                                              float* __restrict__ gated) {
    const int c = blockIdx.x * 256 + threadIdx.x;
    const int ch = blockIdx.y;
    const int b = blockIdx.z;

    float A[16];
#pragma unroll
    for (int s4 = 0; s4 < 16; s4 += 4) {
        float4 v = *(const float4*)&A_log[c * 16 + s4];
        A[s4] = -__expf(v.x); A[s4 + 1] = -__expf(v.y);
        A[s4 + 2] = -__expf(v.z); A[s4 + 3] = -__expf(v.w);
    }
    float h[16];
    const size_t o = (((size_t)b * NCT + ch) * DI + c) * 16;
#pragma unroll
    for (int s4 = 0; s4 < 16; s4 += 4) {
        float4 v = *(const float4*)&hstart[o + s4];
        h[s4] = v.x; h[s4 + 1] = v.y; h[s4 + 2] = v.z; h[s4 + 3] = v.w;
    }

    const size_t m0 = (size_t)b * LL + (size_t)ch * CTL;
#pragma unroll 2
    for (int t = 0; t < CTL; ++t) {
        const size_t m = m0 + t;
        const float dt = dtb[m * DI + c];
        const float uv = u[m * DI + c];
        const float dtu = dt * uv;
        const float* __restrict__ bc = P + m * 96 + 64;   // wave-uniform B then C
        float y = 0.f;
#pragma unroll
        for (int s = 0; s < 16; ++s) {
            const float ab = __expf(dt * A[s]);
            h[s] = ab * h[s] + bc[s] * dtu;
            y += bc[16 + s] * h[s];
        }
        const float zv = zs[m * DI + c];
        gated[m * DI + c] = y * zv;
    }
}

// ---------------------------------------------------------------------------
// Workspace (floats), max extent 21,168,128 (proven footprint):
//   Pp (proj partials) [0, 786432)      (xz dead after conv; Pp dead after reduce)
//   gated [0, 4194304)                  (tscan3 output)
//   hend [4194304, 6291456)  sumdt [6291456, 6356992)   (scan phase)
//   P2_1 [4194304, 6291456)             (GEMM2 partial, after scan)
//   GEMM1 splits: A1s@8388608 A2s@9437184 A3s@10485760
//                 B1s@11534336 B2s@13631488 B3s@15728640  -> dead after GEMM1
//   u [8388608, 12582912), zs [12582912, 16777216)
//   P [16777216, 16973824), dtb [16973824, 21168128)
//   G1s@8388608 G2s@10485760 G3s@12582912, Wo1s@14680064 Wo2s@15728640 Wo3s@16777216
// ---------------------------------------------------------------------------
extern "C" void kernel_launch(void* const* d_in, const int* in_sizes, int n_in,
                              void* d_out, int out_size, void* d_ws, size_t ws_size,
                              hipStream_t stream) {
    const float* inputs = (const float*)d_in[0];
    const float* W_in   = (const float*)d_in[1];
    const float* W_conv = (const float*)d_in[2];
    const float* b_conv = (const float*)d_in[3];
    const float* W_x    = (const float*)d_in[4];
    const float* W_dt   = (const float*)d_in[5];
    const float* b_dt   = (const float*)d_in[6];
    const float* A_log  = (const float*)d_in[7];
    const float* W_out  = (const float*)d_in[8];
    float* out = (float*)d_out;

    float* ws = (float*)d_ws;
    float* xz      = ws;
    float* Pp      = ws;                      // proj partials (4 x 196608)
    float* gated   = ws;
    float* hend    = ws + 4194304;            // 2097152
    float* sumdt   = ws + 6291456;            // 65536
    float* P2_1    = ws + 4194304;            // after scan
    unsigned short* A1s = (unsigned short*)(ws + 8388608);
    unsigned short* A2s = (unsigned short*)(ws + 9437184);
    unsigned short* A3s = (unsigned short*)(ws + 10485760);
    unsigned short* B1s = (unsigned short*)(ws + 11534336);
    unsigned short* B2s = (unsigned short*)(ws + 13631488);
    unsigned short* B3s = (unsigned short*)(ws + 15728640);
    float* u       = ws + 8388608;
    float* zs      = ws + 12582912;
    float* P       = ws + 16777216;
    float* dtb     = ws + 16973824;
    unsigned short* G1s  = (unsigned short*)(ws + 8388608);
    unsigned short* G2s  = (unsigned short*)(ws + 10485760);
    unsigned short* G3s  = (unsigned short*)(ws + 12582912);
    unsigned short* Wo1s = (unsigned short*)(ws + 14680064);
    unsigned short* Wo2s = (unsigned short*)(ws + 15728640);
    unsigned short* Wo3s = (unsigned short*)(ws + 16777216);

    // 0) split inputs and W_in into bf16 triples
    split3<<<2048, 256, 0, stream>>>((const float4*)inputs, (ushort4*)A1s,
                                     (ushort4*)A2s, (ushort4*)A3s, 524288);
    split3<<<2048, 256, 0, stream>>>((const float4*)W_in, (ushort4*)B1s,
                                     (ushort4*)B2s, (ushort4*)B3s, 1048576);
    // 1) xz = inputs @ W_in^T via split-bf16 MFMA
    gemm_mfma_split<<<dim3(32, 16, 1), 256, 0, stream>>>(
        A1s, A2s, A3s, B1s, B2s, B3s, xz, xz, MROWS, 2 * DI, DD, DD);
    // 2) u, zs row-major (overwrites dead A/B splits)
    conv_silu_rm<<<dim3(DI / 256, LL, BB), 256, 0, stream>>>(xz, W_conv, b_conv, u, zs);
    // 3) proj split-K=4 -> partials -> P[m][96]
    proj_gemm_sk<<<dim3(MROWS / 16, 4), 256, 0, stream>>>(u, W_x, Pp);
    proj_reduce<<<192, 256, 0, stream>>>((float4*)P, (const float4*)Pp, 49152);
    // 4) dtb[m][DI]
    dt_gemm<<<dim3(DI / 256, MROWS / 16), 256, 0, stream>>>(P, W_dt, b_dt, dtb);
    // 5) transposed chunked scan -> gated[m][DI]
    tscan1<<<dim3(DI / 256, NCT, BB), 256, 0, stream>>>(dtb, u, P, A_log, hend, sumdt);
    tscan2<<<dim3(BB * DI * SS / 256), 256, 0, stream>>>(hend, sumdt, A_log);
    tscan3<<<dim3(DI / 256, NCT, BB), 256, 0, stream>>>(dtb, u, P, zs, A_log, hend, gated);
    // 6) split gated and W_out
    split3<<<2048, 256, 0, stream>>>((const float4*)gated, (ushort4*)G1s,
                                     (ushort4*)G2s, (ushort4*)G3s, 1048576);
    split3<<<2048, 256, 0, stream>>>((const float4*)W_out, (ushort4*)Wo1s,
                                     (ushort4*)Wo2s, (ushort4*)Wo3s, 524288);
    // 7) out = gated @ W_out^T, split-K=2; then reduce
    gemm_mfma_split<<<dim3(8, 16, 2), 256, 0, stream>>>(
        G1s, G2s, G3s, Wo1s, Wo2s, Wo3s, out, P2_1, MROWS, DD, DI, DI / 2);
    reduce_add_inplace<<<1024, 256, 0, stream>>>((float4*)out, (const float4*)P2_1, 524288);
}

// Round 9
// 382.664 us; speedup vs baseline: 1.3745x; 1.0762x over previous
//
#include <hip/hip_runtime.h>
#include <hip/hip_bf16.h>

// Problem constants
#define BB 2
#define LL 1024
#define DD 1024
#define DI 2048
#define SS 16
#define KK 4
#define RR 64
#define MROWS (BB*LL)   // 2048
#define NCT 32          // t-chunks for scan
#define CTL 32          // steps per chunk (LL / NCT)

typedef __attribute__((ext_vector_type(8))) short short8;     // 8 bf16 = 4 VGPR
typedef __attribute__((ext_vector_type(4))) float floatx4;    // MFMA C/D

// RNE fp32 -> bf16 bits
__device__ __forceinline__ unsigned short f2bf(float v) {
    unsigned int u = __float_as_uint(v);
    return (unsigned short)((u + 0x7FFFu + ((u >> 16) & 1u)) >> 16);
}
__device__ __forceinline__ float bf2f(unsigned short h) {
    return __uint_as_float(((unsigned int)h) << 16);
}
__device__ __forceinline__ void split1(float v, unsigned short& a,
                                       unsigned short& b, unsigned short& c) {
    a = f2bf(v);
    float r = v - bf2f(a);
    b = f2bf(r);
    float r2 = r - bf2f(b);
    c = f2bf(r2);
}

// ---------------------------------------------------------------------------
// split3: fp32[n] -> three bf16[n] (hi, mid, lo), elementwise
// ---------------------------------------------------------------------------
__global__ __launch_bounds__(256) void split3(const float4* __restrict__ src,
                                              ushort4* __restrict__ d1,
                                              ushort4* __restrict__ d2,
                                              ushort4* __restrict__ d3, int n4) {
    for (int i = blockIdx.x * 256 + threadIdx.x; i < n4; i += gridDim.x * 256) {
        const float4 v = src[i];
        ushort4 o1, o2, o3;
        split1(v.x, o1.x, o2.x, o3.x);
        split1(v.y, o1.y, o2.y, o3.y);
        split1(v.z, o1.z, o2.z, o3.z);
        split1(v.w, o1.w, o2.w, o3.w);
        d1[i] = o1; d2[i] = o2; d3[i] = o3;
    }
}

// ---------------------------------------------------------------------------
// Split-bf16 MFMA GEMM (round-4 proven single-phase structure, 60 KB LDS,
// 2 barriers per k-iter).  blockIdx.z = K-split; z=0 -> C0, z>0 -> partials.
// ---------------------------------------------------------------------------
__global__ __launch_bounds__(256, 2) void gemm_mfma_split(
    const unsigned short* __restrict__ A1, const unsigned short* __restrict__ A2,
    const unsigned short* __restrict__ A3,
    const unsigned short* __restrict__ B1, const unsigned short* __restrict__ B2,
    const unsigned short* __restrict__ B3,
    float* __restrict__ C0, float* __restrict__ Cpart,
    int M, int N, int Kstride, int Klen) {
    __shared__ unsigned short As[3][128][40];
    __shared__ unsigned short Bs[3][128][40];
    const int tid = threadIdx.x;
    const int bm = blockIdx.y * 128;
    const int bn = blockIdx.x * 128;
    const int Koff = blockIdx.z * Klen;
    float* __restrict__ C = (blockIdx.z == 0)
        ? C0 : (Cpart + (size_t)(blockIdx.z - 1) * M * N);

    const int lane = tid & 63;
    const int wv = tid >> 6;
    const int lm = lane & 15;
    const int kq = lane >> 4;
    const int wm = (wv >> 1) * 64;
    const int wn = (wv & 1) * 64;

    floatx4 acc[4][4];
    const floatx4 zf = {0.f, 0.f, 0.f, 0.f};
#pragma unroll
    for (int i = 0; i < 4; ++i)
#pragma unroll
        for (int j = 0; j < 4; ++j) acc[i][j] = zf;

    const int ch0 = tid * 2;

    for (int kt = Koff; kt < Koff + Klen; kt += 32) {
#define STAGE(p, SRC_A, SRC_B)                                                          \
        {                                                                               \
            const int r0 = (ch0) >> 2, c0 = ((ch0) & 3) * 8;                            \
            const int r1 = (ch0 + 1) >> 2, c1 = ((ch0 + 1) & 3) * 8;                    \
            *(short8*)&As[p][r0][c0] = *(const short8*)&SRC_A[(size_t)(bm + r0) * Kstride + kt + c0]; \
            *(short8*)&As[p][r1][c1] = *(const short8*)&SRC_A[(size_t)(bm + r1) * Kstride + kt + c1]; \
            *(short8*)&Bs[p][r0][c0] = *(const short8*)&SRC_B[(size_t)(bn + r0) * Kstride + kt + c0]; \
            *(short8*)&Bs[p][r1][c1] = *(const short8*)&SRC_B[(size_t)(bn + r1) * Kstride + kt + c1]; \
        }
        STAGE(0, A1, B1)
        STAGE(1, A2, B2)
        STAGE(2, A3, B3)
#undef STAGE
        __syncthreads();

        short8 af[3][4];
#pragma unroll
        for (int p = 0; p < 3; ++p)
#pragma unroll
            for (int i = 0; i < 4; ++i)
                af[p][i] = *(const short8*)&As[p][wm + i * 16 + lm][kq * 8];

#define PROD(p, bfq)                                                                     \
        _Pragma("unroll")                                                                \
        for (int i = 0; i < 4; ++i)                                                      \
            _Pragma("unroll")                                                            \
            for (int j = 0; j < 4; ++j)                                                  \
                acc[i][j] = __builtin_amdgcn_mfma_f32_16x16x32_bf16(af[p][i], bfq[j],    \
                                                                    acc[i][j], 0, 0, 0);
        {
            short8 bfq[4];
#pragma unroll
            for (int j = 0; j < 4; ++j) bfq[j] = *(const short8*)&Bs[0][wn + j * 16 + lm][kq * 8];
            PROD(0, bfq)
            PROD(1, bfq)
            PROD(2, bfq)
        }
        {
            short8 bfq[4];
#pragma unroll
            for (int j = 0; j < 4; ++j) bfq[j] = *(const short8*)&Bs[1][wn + j * 16 + lm][kq * 8];
            PROD(0, bfq)
            PROD(1, bfq)
        }
        {
            short8 bfq[4];
#pragma unroll
            for (int j = 0; j < 4; ++j) bfq[j] = *(const short8*)&Bs[2][wn + j * 16 + lm][kq * 8];
            PROD(0, bfq)
        }
#undef PROD
        __syncthreads();
    }

#pragma unroll
    for (int i = 0; i < 4; ++i) {
        const int mrow = bm + wm + i * 16 + kq * 4;
#pragma unroll
        for (int j = 0; j < 4; ++j) {
            const int col = bn + wn + j * 16 + lm;
#pragma unroll
            for (int r = 0; r < 4; ++r)
                C[(size_t)(mrow + r) * N + col] = acc[i][j][r];
        }
    }
}

// ---------------------------------------------------------------------------
// dst += src0 + src1 + src2   (split-K=4 final reduce)
// ---------------------------------------------------------------------------
__global__ __launch_bounds__(256) void reduce_add3(float4* __restrict__ dst,
                                                   const float4* __restrict__ src,
                                                   int n4) {
    for (int i = blockIdx.x * 256 + threadIdx.x; i < n4; i += gridDim.x * 256) {
        float4 a = dst[i];
        const float4 p0 = src[i];
        const float4 p1 = src[i + (size_t)n4];
        const float4 p2 = src[i + (size_t)2 * n4];
        a.x += p0.x + p1.x + p2.x;
        a.y += p0.y + p1.y + p2.y;
        a.z += p0.z + p1.z + p2.z;
        a.w += p0.w + p1.w + p2.w;
        dst[i] = a;
    }
}

// ---------------------------------------------------------------------------
// Depthwise causal conv (K=4) + bias + silu, row-major outputs (unchanged)
// ---------------------------------------------------------------------------
__global__ __launch_bounds__(256) void conv_silu_rm(const float* __restrict__ xz,
                                                    const float* __restrict__ Wc,
                                                    const float* __restrict__ bc,
                                                    float* __restrict__ u,
                                                    float* __restrict__ zs) {
    const int c = blockIdx.x * 256 + threadIdx.x;
    const int t = blockIdx.y;
    const int b = blockIdx.z;
    const float* xcol = xz + (size_t)b * LL * (2 * DI) + c;
    const float w0 = Wc[c * 4 + 0], w1 = Wc[c * 4 + 1];
    const float w2 = Wc[c * 4 + 2], w3 = Wc[c * 4 + 3];
    float acc = bc[c];
    if (t >= 3) acc += xcol[(size_t)(t - 3) * (2 * DI)] * w0;
    if (t >= 2) acc += xcol[(size_t)(t - 2) * (2 * DI)] * w1;
    if (t >= 1) acc += xcol[(size_t)(t - 1) * (2 * DI)] * w2;
    acc += xcol[(size_t)t * (2 * DI)] * w3;
    const float zv = xcol[(size_t)t * (2 * DI) + DI];
    const size_t o = ((size_t)b * LL + t) * DI + c;
    u[o]  = acc / (1.f + __expf(-acc));
    zs[o] = zv / (1.f + __expf(-zv));
}

// ---------------------------------------------------------------------------
// proj split-K=4: Pp[kz][m][96] = u[m][kz-window] @ W_x^T  (512 blocks)
// ---------------------------------------------------------------------------
__global__ __launch_bounds__(256) void proj_gemm_sk(const float* __restrict__ U,
                                                    const float* __restrict__ Wx,
                                                    float* __restrict__ Pp) {
    const int BKp = 64;
    __shared__ float Us[16][BKp + 1];
    __shared__ float Ws[96][BKp + 1];
    const int tid = threadIdx.x;
    const int m0 = blockIdx.x * 16;
    const int Koff = blockIdx.y * (DI / 4);
    float* __restrict__ P = Pp + (size_t)blockIdx.y * MROWS * 96;
    const int tx = tid & 31;
    const int ty = tid >> 5;
    float acc[2][3] = {{0.f, 0.f, 0.f}, {0.f, 0.f, 0.f}};

    for (int kt = Koff; kt < Koff + DI / 4; kt += BKp) {
        {
            const int r = tid >> 4;
            const int c4 = (tid & 15) << 2;
            float4 v = *(const float4*)&U[(size_t)(m0 + r) * DI + kt + c4];
            Us[r][c4] = v.x; Us[r][c4 + 1] = v.y; Us[r][c4 + 2] = v.z; Us[r][c4 + 3] = v.w;
        }
#pragma unroll
        for (int i = 0; i < 6; ++i) {
            const int idx = tid + i * 256;
            const int r = idx >> 4;
            const int c4 = (idx & 15) << 2;
            float4 v = *(const float4*)&Wx[(size_t)r * DI + kt + c4];
            Ws[r][c4] = v.x; Ws[r][c4 + 1] = v.y; Ws[r][c4 + 2] = v.z; Ws[r][c4 + 3] = v.w;
        }
        __syncthreads();
#pragma unroll 8
        for (int k = 0; k < BKp; ++k) {
            const float um0 = Us[ty * 2][k];
            const float um1 = Us[ty * 2 + 1][k];
#pragma unroll
            for (int j = 0; j < 3; ++j) {
                const float w = Ws[tx + 32 * j][k];
                acc[0][j] += um0 * w;
                acc[1][j] += um1 * w;
            }
        }
        __syncthreads();
    }
#pragma unroll
    for (int i = 0; i < 2; ++i)
#pragma unroll
        for (int j = 0; j < 3; ++j)
            P[(size_t)(m0 + ty * 2 + i) * 96 + tx + 32 * j] = acc[i][j];
}

// ---------------------------------------------------------------------------
// proj reduce: P[i] = sum_{kz<4} Pp[kz][i]
// ---------------------------------------------------------------------------
__global__ __launch_bounds__(256) void proj_reduce(float4* __restrict__ P,
                                                   const float4* __restrict__ Pp,
                                                   int n4) {
    for (int i = blockIdx.x * 256 + threadIdx.x; i < n4; i += gridDim.x * 256) {
        const float4 a = Pp[i];
        const float4 b = Pp[i + (size_t)n4];
        const float4 c = Pp[i + (size_t)2 * n4];
        const float4 d = Pp[i + (size_t)3 * n4];
        P[i] = make_float4(a.x + b.x + c.x + d.x, a.y + b.y + c.y + d.y,
                           a.z + b.z + c.z + d.z, a.w + b.w + c.w + d.w);
    }
}

// ---------------------------------------------------------------------------
// dt[m][c] = softplus(P[m][:64] @ W_dt^T + b_dt)  (unchanged)
// ---------------------------------------------------------------------------
__global__ __launch_bounds__(256) void dt_gemm(const float* __restrict__ P,
                                               const float* __restrict__ Wdt,
                                               const float* __restrict__ bdt,
                                               float* __restrict__ dtb) {
    __shared__ float ps[16][68];
    const int tid = threadIdx.x;
    const int c = blockIdx.x * 256 + tid;
    const int m0 = blockIdx.y * 16;
    {
        const int r = tid >> 4;
        const int c4 = (tid & 15) << 2;
        float4 v = *(const float4*)&P[(size_t)(m0 + r) * 96 + c4];
        ps[r][c4] = v.x; ps[r][c4 + 1] = v.y; ps[r][c4 + 2] = v.z; ps[r][c4 + 3] = v.w;
    }
    float w[64];
#pragma unroll
    for (int r4 = 0; r4 < 64; r4 += 4) {
        float4 v = *(const float4*)&Wdt[(size_t)c * 64 + r4];
        w[r4] = v.x; w[r4 + 1] = v.y; w[r4 + 2] = v.z; w[r4 + 3] = v.w;
    }
    const float bd = bdt[c];
    __syncthreads();
#pragma unroll 4
    for (int m = 0; m < 16; ++m) {
        float acc = bd;
#pragma unroll
        for (int r4 = 0; r4 < 64; r4 += 4) {
            float4 p = *(const float4*)&ps[m][r4];
            acc += p.x * w[r4] + p.y * w[r4 + 1] + p.z * w[r4 + 2] + p.w * w[r4 + 3];
        }
        const float sp = (acc > 20.f) ? acc : __logf(1.f + __expf(acc));
        dtb[(size_t)(m0 + m) * DI + c] = sp;
    }
}

// ---------------------------------------------------------------------------
// Transposed chunked scan (unchanged from round 8)
// ---------------------------------------------------------------------------
__global__ __launch_bounds__(256) void tscan1(const float* __restrict__ dtb,
                                              const float* __restrict__ u,
                                              const float* __restrict__ P,
                                              const float* __restrict__ A_log,
                                              float* __restrict__ hend,
                                              float* __restrict__ sumdt) {
    const int c = blockIdx.x * 256 + threadIdx.x;
    const int ch = blockIdx.y;
    const int b = blockIdx.z;

    float A[16];
#pragma unroll
    for (int s4 = 0; s4 < 16; s4 += 4) {
        float4 v = *(const float4*)&A_log[c * 16 + s4];
        A[s4] = -__expf(v.x); A[s4 + 1] = -__expf(v.y);
        A[s4 + 2] = -__expf(v.z); A[s4 + 3] = -__expf(v.w);
    }
    float h[16];
#pragma unroll
    for (int s = 0; s < 16; ++s) h[s] = 0.f;
    float sd = 0.f;

    const size_t m0 = (size_t)b * LL + (size_t)ch * CTL;
#pragma unroll 2
    for (int t = 0; t < CTL; ++t) {
        const size_t m = m0 + t;
        const float dt = dtb[m * DI + c];
        const float uv = u[m * DI + c];
        const float dtu = dt * uv;
        sd += dt;
        const float* __restrict__ bc = P + m * 96 + 64;
#pragma unroll
        for (int s = 0; s < 16; ++s) {
            const float ab = __expf(dt * A[s]);
            h[s] = ab * h[s] + bc[s] * dtu;
        }
    }
    const size_t o = (((size_t)b * NCT + ch) * DI + c) * 16;
#pragma unroll
    for (int s4 = 0; s4 < 16; s4 += 4)
        *(float4*)&hend[o + s4] = make_float4(h[s4], h[s4 + 1], h[s4 + 2], h[s4 + 3]);
    sumdt[((size_t)b * NCT + ch) * DI + c] = sd;
}

// ---------------------------------------------------------------------------
__global__ __launch_bounds__(256) void tscan2(float* __restrict__ hend,
                                              const float* __restrict__ sumdt,
                                              const float* __restrict__ A_log) {
    const int id = blockIdx.x * 256 + threadIdx.x;
    const int s = id & 15;
    const int c = (id >> 4) & (DI - 1);
    const int b = id >> 15;
    const float Aval = -__expf(A_log[c * 16 + s]);
    float hs = 0.f;
#pragma unroll
    for (int g = 0; g < 4; ++g) {
        float he[8], sd[8];
#pragma unroll
        for (int j = 0; j < 8; ++j) {
            const size_t base = ((size_t)b * NCT + (g * 8 + j)) * DI + c;
            he[j] = hend[base * 16 + s];
            sd[j] = sumdt[base];
        }
#pragma unroll
        for (int j = 0; j < 8; ++j) {
            const size_t base = ((size_t)b * NCT + (g * 8 + j)) * DI + c;
            hend[base * 16 + s] = hs;
            hs = __expf(Aval * sd[j]) * hs + he[j];
        }
    }
}

// ---------------------------------------------------------------------------
__global__ __launch_bounds__(256) void tscan3(const float* __restrict__ dtb,
                                              const float* __restrict__ u,
                                              const float* __restrict__ P,
                                              const float* __restrict__ zs,
                                              const float* __restrict__ A_log,
                                              const float* __restrict__ hstart,
                                              float* __restrict__ gated) {
    const int c = blockIdx.x * 256 + threadIdx.x;
    const int ch = blockIdx.y;
    const int b = blockIdx.z;

    float A[16];
#pragma unroll
    for (int s4 = 0; s4 < 16; s4 += 4) {
        float4 v = *(const float4*)&A_log[c * 16 + s4];
        A[s4] = -__expf(v.x); A[s4 + 1] = -__expf(v.y);
        A[s4 + 2] = -__expf(v.z); A[s4 + 3] = -__expf(v.w);
    }
    float h[16];
    const size_t o = (((size_t)b * NCT + ch) * DI + c) * 16;
#pragma unroll
    for (int s4 = 0; s4 < 16; s4 += 4) {
        float4 v = *(const float4*)&hstart[o + s4];
        h[s4] = v.x; h[s4 + 1] = v.y; h[s4 + 2] = v.z; h[s4 + 3] = v.w;
    }

    const size_t m0 = (size_t)b * LL + (size_t)ch * CTL;
#pragma unroll 2
    for (int t = 0; t < CTL; ++t) {
        const size_t m = m0 + t;
        const float dt = dtb[m * DI + c];
        const float uv = u[m * DI + c];
        const float dtu = dt * uv;
        const float* __restrict__ bc = P + m * 96 + 64;
        float y = 0.f;
#pragma unroll
        for (int s = 0; s < 16; ++s) {
            const float ab = __expf(dt * A[s]);
            h[s] = ab * h[s] + bc[s] * dtu;
            y += bc[16 + s] * h[s];
        }
        const float zv = zs[m * DI + c];
        gated[m * DI + c] = y * zv;
    }
}

// ---------------------------------------------------------------------------
// Workspace (floats), max extent 21,168,128 (proven footprint):
//   phase A (pre-conv): xz [0,8388608); A/B splits [8388608,17825792)
//   phase B (post-conv): Pp proj partials [0,786432); u [8388608,12582912),
//       zs [12582912,16777216), P [16777216,16973824), dtb [16973824,21168128)
//   phase C (scan): gated [0,4194304), hend [4194304,6291456),
//       sumdt [6291456,6356992)
//   phase D (GEMM2): G1s@8388608 G2s@10485760 G3s@12582912,
//       Wo1s@14680064 Wo2s@15728640 Wo3s@16777216;
//       P2 partials z=1..3 at [0,6291456)  (gated+hend dead)
// ---------------------------------------------------------------------------
extern "C" void kernel_launch(void* const* d_in, const int* in_sizes, int n_in,
                              void* d_out, int out_size, void* d_ws, size_t ws_size,
                              hipStream_t stream) {
    const float* inputs = (const float*)d_in[0];
    const float* W_in   = (const float*)d_in[1];
    const float* W_conv = (const float*)d_in[2];
    const float* b_conv = (const float*)d_in[3];
    const float* W_x    = (const float*)d_in[4];
    const float* W_dt   = (const float*)d_in[5];
    const float* b_dt   = (const float*)d_in[6];
    const float* A_log  = (const float*)d_in[7];
    const float* W_out  = (const float*)d_in[8];
    float* out = (float*)d_out;

    float* ws = (float*)d_ws;
    float* xz      = ws;
    float* Pp      = ws;                      // proj partials (4 x 196608)
    float* gated   = ws;
    float* P2p     = ws;                      // GEMM2 partials z=1..3 (3 x 2097152)
    float* hend    = ws + 4194304;            // 2097152
    float* sumdt   = ws + 6291456;            // 65536
    unsigned short* A1s = (unsigned short*)(ws + 8388608);
    unsigned short* A2s = (unsigned short*)(ws + 9437184);
    unsigned short* A3s = (unsigned short*)(ws + 10485760);
    unsigned short* B1s = (unsigned short*)(ws + 11534336);
    unsigned short* B2s = (unsigned short*)(ws + 13631488);
    unsigned short* B3s = (unsigned short*)(ws + 15728640);
    float* u       = ws + 8388608;
    float* zs      = ws + 12582912;
    float* P       = ws + 16777216;
    float* dtb     = ws + 16973824;
    unsigned short* G1s  = (unsigned short*)(ws + 8388608);
    unsigned short* G2s  = (unsigned short*)(ws + 10485760);
    unsigned short* G3s  = (unsigned short*)(ws + 12582912);
    unsigned short* Wo1s = (unsigned short*)(ws + 14680064);
    unsigned short* Wo2s = (unsigned short*)(ws + 15728640);
    unsigned short* Wo3s = (unsigned short*)(ws + 16777216);

    // 0) split inputs and W_in into bf16 triples
    split3<<<2048, 256, 0, stream>>>((const float4*)inputs, (ushort4*)A1s,
                                     (ushort4*)A2s, (ushort4*)A3s, 524288);
    split3<<<2048, 256, 0, stream>>>((const float4*)W_in, (ushort4*)B1s,
                                     (ushort4*)B2s, (ushort4*)B3s, 1048576);
    // 1) xz = inputs @ W_in^T via split-bf16 MFMA (no split-K: 512 blocks)
    gemm_mfma_split<<<dim3(32, 16, 1), 256, 0, stream>>>(
        A1s, A2s, A3s, B1s, B2s, B3s, xz, xz, MROWS, 2 * DI, DD, DD);
    // 2) u, zs row-major (overwrites dead A/B splits)
    conv_silu_rm<<<dim3(DI / 256, LL, BB), 256, 0, stream>>>(xz, W_conv, b_conv, u, zs);
    // 3) proj split-K=4 -> partials -> P[m][96]
    proj_gemm_sk<<<dim3(MROWS / 16, 4), 256, 0, stream>>>(u, W_x, Pp);
    proj_reduce<<<192, 256, 0, stream>>>((float4*)P, (const float4*)Pp, 49152);
    // 4) dtb[m][DI]
    dt_gemm<<<dim3(DI / 256, MROWS / 16), 256, 0, stream>>>(P, W_dt, b_dt, dtb);
    // 5) transposed chunked scan -> gated[m][DI]
    tscan1<<<dim3(DI / 256, NCT, BB), 256, 0, stream>>>(dtb, u, P, A_log, hend, sumdt);
    tscan2<<<dim3(BB * DI * SS / 256), 256, 0, stream>>>(hend, sumdt, A_log);
    tscan3<<<dim3(DI / 256, NCT, BB), 256, 0, stream>>>(dtb, u, P, zs, A_log, hend, gated);
    // 6) split gated and W_out
    split3<<<2048, 256, 0, stream>>>((const float4*)gated, (ushort4*)G1s,
                                     (ushort4*)G2s, (ushort4*)G3s, 1048576);
    split3<<<2048, 256, 0, stream>>>((const float4*)W_out, (ushort4*)Wo1s,
                                     (ushort4*)Wo2s, (ushort4*)Wo3s, 524288);
    // 7) out = gated @ W_out^T, split-K=4 (512 blocks, 2 blocks/CU):
    //    z=0 -> out, z=1..3 -> P2p (dead gated/hend region)
    gemm_mfma_split<<<dim3(8, 16, 4), 256, 0, stream>>>(
        G1s, G2s, G3s, Wo1s, Wo2s, Wo3s, out, P2p, MROWS, DD, DI, DI / 4);
    // 7b) out += sum of 3 partials
    reduce_add3<<<2048, 256, 0, stream>>>((float4*)out, (const float4*)P2p, 524288);
}